// Round 25
// baseline (133.231 us; speedup 1.0000x reference)
//
#include <hip/hip_runtime.h>
#include <hip/hip_bf16.h>

#define D_MODEL 512
#define BATCH 4
#define SEQ 2048
#define ROWS (BATCH*SEQ)   // 8192

typedef unsigned short u16;
typedef short bf16x8 __attribute__((ext_vector_type(8)));
typedef float f32x4 __attribute__((ext_vector_type(4)));

__device__ __forceinline__ float bf2f(u16 u) {
    union { unsigned int i; float f; } v;
    v.i = ((unsigned int)u) << 16;
    return v.f;
}
__device__ __forceinline__ u16 f2bf(float f) {
    union { float f; unsigned int i; } v;
    v.f = f;
    unsigned int x = v.i;
    unsigned int r = (x >> 16) & 1u;
    x += 0x7fffu + r;           // round-to-nearest-even
    return (u16)(x >> 16);
}

template<int N> __device__ __forceinline__ void waitv() {
    static_assert(N==0 || N==3 || N==4 || N==5 || N==8, "unsupported vmcnt");
    if constexpr (N == 0) asm volatile("s_waitcnt vmcnt(0)" ::: "memory");
    if constexpr (N == 3) asm volatile("s_waitcnt vmcnt(3)" ::: "memory");
    if constexpr (N == 4) asm volatile("s_waitcnt vmcnt(4)" ::: "memory");
    if constexpr (N == 5) asm volatile("s_waitcnt vmcnt(5)" ::: "memory");
    if constexpr (N == 8) asm volatile("s_waitcnt vmcnt(8)" ::: "memory");
}

// ---------------- fused prep: x -> hi only; weights hi-only; bias concat ----
__global__ __launch_bounds__(256)
void prep_kernel(const float* __restrict__ x,
                 const float* __restrict__ Wq, const float* __restrict__ Wk,
                 const float* __restrict__ Wv, const float* __restrict__ Wo,
                 const float* __restrict__ bq, const float* __restrict__ bk,
                 const float* __restrict__ bv,
                 u16* __restrict__ xh,
                 u16* __restrict__ whh, u16* __restrict__ woh,
                 float* __restrict__ bqkv)
{
    const int blk = blockIdx.x;
    const int tid = threadIdx.x;
    const int WE = 262144;
    if (blk >= 5120) {
        int i = (blk - 5120) * 256 + tid;
        if (i < 1536)
            bqkv[i] = (i < 512) ? bq[i] : (i < 1024) ? bk[i - 512] : bv[i - 1024];
        return;
    }
    const float* src; u16 *dh; int i;
    if (blk < 4096) {
        src = x; dh = xh;
        i = (blk * 256 + tid) * 4;
    } else {
        int w = (blk - 4096) >> 8;
        src = (w == 0) ? Wq : (w == 1) ? Wk : (w == 2) ? Wv : Wo;
        dh  = (w < 3) ? whh + w * WE : woh;
        i = (((blk - 4096) & 255) * 256 + tid) * 4;
    }
    float4 v = *(const float4*)(src + i);
    u16 hh[4] = { f2bf(v.x), f2bf(v.y), f2bf(v.z), f2bf(v.w) };
    *(ushort4*)(dh + i) = make_ushort4(hh[0], hh[1], hh[2], hh[3]);
}

// ======== shared GEMM pieces ========
#define GEMM_PROLOG_ID                                                         \
    const int tid  = threadIdx.x;                                              \
    const int lane = tid & 63;                                                 \
    const int wave = tid >> 6;                                                 \
    const int wr = wave >> 1, wc = wave & 1;                                   \
    const int gx = gridDim.x, gy = gridDim.y;                                  \
    int nwg = gx * gy * gridDim.z;                                             \
    int wg  = blockIdx.x + gx * (blockIdx.y + gy * blockIdx.z);                \
    int id  = (wg & 7) * (nwg >> 3) + (wg >> 3);                               \
    int bx, by, bz;

#define GEMM_PROLOG_BODY                                                       \
    const long aBase = (long)bz * aStride + (long)(bx * 128) * lda;            \
    const long bBase = (long)bz * bStride + (long)(by * BN) * ldb;             \
    const u16* csrc[CPW];                                                      \
    unsigned cdst[CPW];                                                        \
    _Pragma("unroll")                                                          \
    for (int i = 0; i < CPW; ++i) {                                            \
        int c = wave + i * 4;                                                  \
        const u16* sb; int ld, lofs, row;                                      \
        if (c < AT * ACH) {                                                    \
            int t = c >> 3;                                                    \
            row = (c & 7) * 16;                                                \
            sb = (t == 0 ? Ah : Al) + aBase;                                   \
            ld = lda; lofs = t * TILE_A;                                       \
        } else {                                                               \
            int cb = c - AT * ACH;                                             \
            int t = cb / BCH;                                                  \
            row = (cb % BCH) * 16;                                             \
            sb = (t == 0 ? Bh : Bl) + bBase;                                   \
            ld = ldb; lofs = AT * TILE_A + t * TILE_B;                         \
        }                                                                      \
        csrc[i] = sb + (long)(row + (lane >> 2)) * ld + (lane & 3) * 8;        \
        cdst[i] = lofs + row * 32;                                             \
    }                                                                          \
    f32x4 acc[4][NF] = {};                                                     \
    const int frow = lane & 15;                                                \
    const int kofs = (lane >> 4) * 8;

#define GEMM_CONSTS                                                            \
    constexpr int BN     = 32 * NF;                                            \
    constexpr int TILE_A = 128 * 32;                                           \
    constexpr int TILE_B = BN * 32;                                            \
    constexpr int ACH    = 8;                                                  \
    constexpr int BCH    = BN / 16;                                            \
    constexpr int NCH    = AT*ACH + BT*BCH;                                    \
    constexpr int CPW    = NCH / 4;                                            \
    constexpr int BUFSZ  = AT*TILE_A + BT*TILE_B;

#define GEMM_COMPUTE(bb_)                                                      \
    {                                                                          \
        const int bb = (bb_);                                                  \
        bf16x8 aH[4], aL[4], bH[NF], bL[NF];                                   \
        _Pragma("unroll")                                                      \
        for (int m = 0; m < 4; ++m) {                                          \
            int rA = wr*64 + m*16 + frow;                                      \
            aH[m] = *(const bf16x8*)&lds[bb + rA*32 + kofs];                   \
            if constexpr (AT == 2)                                             \
                aL[m] = *(const bf16x8*)&lds[bb + TILE_A + rA*32 + kofs];      \
        }                                                                      \
        _Pragma("unroll")                                                      \
        for (int n = 0; n < NF; ++n) {                                         \
            int rB = wc*(NF*16) + n*16 + frow;                                 \
            bH[n] = *(const bf16x8*)&lds[bb + AT*TILE_A + rB*32 + kofs];       \
            if constexpr (BT == 2)                                             \
                bL[n] = *(const bf16x8*)&lds[bb + AT*TILE_A + TILE_B + rB*32 + kofs]; \
        }                                                                      \
        _Pragma("unroll")                                                      \
        for (int m = 0; m < 4; ++m)                                            \
            _Pragma("unroll")                                                  \
            for (int n = 0; n < NF; ++n) {                                     \
                acc[m][n] = __builtin_amdgcn_mfma_f32_16x16x32_bf16(aH[m], bH[n], acc[m][n], 0, 0, 0); \
                if constexpr (BT == 2)                                         \
                    acc[m][n] = __builtin_amdgcn_mfma_f32_16x16x32_bf16(aH[m], bL[n], acc[m][n], 0, 0, 0); \
                if constexpr (AT == 2)                                         \
                    acc[m][n] = __builtin_amdgcn_mfma_f32_16x16x32_bf16(aL[m], bH[n], acc[m][n], 0, 0, 0); \
            }                                                                  \
    }

// Double-buffer staged epilogue (gemm2: hi+lo side-by-side buffers).
#define GEMM_EPILOG_STAGED                                                     \
    {                                                                          \
    const int rr = (lane >> 4) * 4;                                            \
    __syncthreads();                                                           \
    if (emode == 0) {                                                          \
        float* ldsF = (float*)lds;                                             \
        _Pragma("unroll")                                                      \
        for (int n = 0; n < NF; ++n) {                                         \
            int c = wc*(NF*16) + n*16 + frow;                                  \
            float bv_ = ebias ? ebias[by*BN + c] : 0.0f;                       \
            _Pragma("unroll")                                                  \
            for (int m = 0; m < 4; ++m)                                        \
                _Pragma("unroll")                                              \
                for (int j = 0; j < 4; ++j)                                    \
                    ldsF[(wr*64 + m*16 + rr + j)*(BN+4) + c] = acc[m][n][j]*scale + bv_; \
        }                                                                      \
        __syncthreads();                                                       \
        for (int idx = tid; idx < 128*(BN/4); idx += 256) {                    \
            int row = idx / (BN/4), c4 = (idx % (BN/4)) * 4;                   \
            *(float4*)&outF[(long)bz*cStride + (long)(bx*128+row)*ldc + by*BN + c4] = \
                *(float4*)&ldsF[row*(BN+4) + c4];                              \
        }                                                                      \
    } else {                                                                   \
        u16* ldsH = (u16*)lds;                                                 \
        u16* ldsL = (u16*)lds + 128*(BN+12);                                   \
        _Pragma("unroll")                                                      \
        for (int n = 0; n < NF; ++n) {                                         \
            int c = wc*(NF*16) + n*16 + frow;                                  \
            float bv_ = ebias ? ebias[by*BN + c] : 0.0f;                       \
            _Pragma("unroll")                                                  \
            for (int m = 0; m < 4; ++m)                                        \
                _Pragma("unroll")                                              \
                for (int j = 0; j < 4; ++j) {                                  \
                    int r = wr*64 + m*16 + rr + j;                             \
                    float val = acc[m][n][j]*scale + bv_;                      \
                    u16 h = f2bf(val);                                         \
                    ldsH[r*(BN+12) + c] = h;                                   \
                    if (eoutL) ldsL[r*(BN+12) + c] = f2bf(val - bf2f(h));      \
                }                                                              \
        }                                                                      \
        __syncthreads();                                                       \
        for (int idx = tid; idx < 128*(BN/8); idx += 256) {                    \
            int row = idx / (BN/8), c8 = (idx % (BN/8)) * 8;                   \
            long o = (long)bz*cStride + (long)(bx*128+row)*ldc + by*BN + c8;   \
            *(bf16x8*)&eoutH[o] = *(bf16x8*)&ldsH[row*(BN+12) + c8];           \
            if (eoutL) *(bf16x8*)&eoutL[o] = *(bf16x8*)&ldsL[row*(BN+12) + c8]; \
        }                                                                      \
    }                                                                          \
    }

// Sequential single-buffer staged epilogue (gemm3): hi pass then lo pass
// through ONE [128][BN+12] buffer -> LDS stays at 3*BUFSZ (occupancy-safe).
#define GEMM_EPILOG_SEQ                                                        \
    {                                                                          \
    const int rr = (lane >> 4) * 4;                                            \
    if (emode == 2) {                                                          \
        u16* ldsT = (u16*)lds;   /* [BN][136]: transposed tile */              \
        __syncthreads();                                                       \
        _Pragma("unroll")                                                      \
        for (int n = 0; n < NF; ++n) {                                         \
            int c = wc*(NF*16) + n*16 + frow;                                  \
            float bv_ = ebias ? ebias[by*BN + c] : 0.0f;                       \
            _Pragma("unroll")                                                  \
            for (int m = 0; m < 4; ++m)                                        \
                _Pragma("unroll")                                              \
                for (int j = 0; j < 4; ++j)                                    \
                    ldsT[c*136 + (wr*64 + m*16 + rr + j)] = f2bf(acc[m][n][j]*scale + bv_); \
        }                                                                      \
        __syncthreads();                                                       \
        int b = bx >> 4, mrowBase = (bx & 15) * 128;                           \
        for (int idx = tid; idx < BN*16; idx += 256) {                         \
            int crow = idx >> 4, r8 = (idx & 15) * 8;                          \
            *(bf16x8*)&eoutH[(long)b*1048576 + (long)(by*BN + crow)*2048 + mrowBase + r8] = \
                *(bf16x8*)&ldsT[crow*136 + r8];                                \
        }                                                                      \
    } else {                                                                   \
        u16* ldsH = (u16*)lds;                                                 \
        const int parts = eoutL ? 2 : 1;                                       \
        for (int part = 0; part < parts; ++part) {                             \
            u16* dstG = part ? eoutL : eoutH;                                  \
            __syncthreads();                                                   \
            _Pragma("unroll")                                                  \
            for (int n = 0; n < NF; ++n) {                                     \
                int c = wc*(NF*16) + n*16 + frow;                              \
                float bv_ = ebias ? ebias[by*BN + c] : 0.0f;                   \
                _Pragma("unroll")                                              \
                for (int m = 0; m < 4; ++m)                                    \
                    _Pragma("unroll")                                          \
                    for (int j = 0; j < 4; ++j) {                              \
                        int r = wr*64 + m*16 + rr + j;                         \
                        float val = acc[m][n][j]*scale + bv_;                  \
                        u16 h = f2bf(val);                                     \
                        ldsH[r*(BN+12) + c] = part ? f2bf(val - bf2f(h)) : h;  \
                    }                                                          \
            }                                                                  \
            __syncthreads();                                                   \
            for (int idx = tid; idx < 128*(BN/8); idx += 256) {                \
                int row = idx / (BN/8), c8 = (idx % (BN/8)) * 8;               \
                *(bf16x8*)&dstG[(long)bz*cStride + (long)(bx*128+row)*ldc + by*BN + c8] = \
                    *(bf16x8*)&ldsH[row*(BN+12) + c8];                         \
            }                                                                  \
        }                                                                      \
    }                                                                          \
    }

// ---- 2-buffer variant (final projection) ----
template<int NF, int AT, int BT>
__global__ __launch_bounds__(256)
void gemm2(const u16* __restrict__ Ah, const u16* __restrict__ Al,
           const u16* __restrict__ Bh, const u16* __restrict__ Bl,
           const float* __restrict__ bias,
           float* __restrict__ outF, u16* __restrict__ outH, u16* __restrict__ outL,
           int K, int lda, int ldb, int ldc,
           long aStride, long bStride, long cStride,
           float scale, int mode)
{
    GEMM_CONSTS
    GEMM_PROLOG_ID
    bx = id % gx;
    by = (id / gx) % gy;
    bz = id / (gx * gy);
    GEMM_PROLOG_BODY
    constexpr int EPI1 = 2 * 128*(BN+12);
    constexpr int EPI0 = 256*(BN+4);
    constexpr int L1   = (2*BUFSZ > EPI1) ? 2*BUFSZ : EPI1;
    constexpr int LDSN = (L1 > EPI0) ? L1 : EPI0;
    __shared__ u16 lds[LDSN];
    auto stage = [&](int buf, int k0) {
        #pragma unroll
        for (int i = 0; i < CPW; ++i)
            __builtin_amdgcn_global_load_lds(
                (const __attribute__((address_space(1))) unsigned int*)(csrc[i] + k0),
                (__attribute__((address_space(3))) unsigned int*)(&lds[buf * BUFSZ + cdst[i]]),
                16, 0, 0);
    };
    const int nt = K >> 5;
    stage(0, 0);
    __syncthreads();
    int cur = 0;
    for (int t = 0; t < nt; ++t) {
        if (t + 1 < nt) stage(cur ^ 1, (t + 1) << 5);
        GEMM_COMPUTE(cur * BUFSZ)
        __syncthreads();
        cur ^= 1;
    }
    int emode = mode; const float* ebias = bias; u16* eoutH = outH; u16* eoutL = outL;
    GEMM_EPILOG_STAGED
}

// ---- ring-3 counted-vmcnt variant ----
// DEC=1 (QKV fused): inner=id%(3*(512/BN)) -> (by, bz weight-slice), bx outer.
// DEC=2 (PV): inner=id%16 -> (by&3, bz>>2), bx=id>>4.
template<int NF, int AT, int BT, int DEC = 0>
__global__ __launch_bounds__(256)
void gemm3(const u16* __restrict__ Ah, const u16* __restrict__ Al,
           const u16* __restrict__ Bh, const u16* __restrict__ Bl,
           const float* __restrict__ bias,
           float* __restrict__ outF, u16* __restrict__ outH, u16* __restrict__ outL,
           u16* __restrict__ outQ, u16* __restrict__ outK, u16* __restrict__ outV,
           int K, int lda, int ldb, int ldc,
           long aStride, long bStride, long cStride,
           float scale, int mode)
{
    GEMM_CONSTS
    GEMM_PROLOG_ID
    if constexpr (DEC == 1) {
        constexpr int NBY = 512 / BN;
        constexpr int INN = 3 * NBY;
        int inner = id % INN;
        by = inner % NBY;
        bz = inner / NBY;
        bx = id / INN;
    } else if constexpr (DEC == 2) {
        int inner = id % 16;
        by = inner & 3;
        bz = inner >> 2;
        bx = id >> 4;
    } else {
        bx = id % gx;
        by = (id / gx) % gy;
        bz = id / (gx * gy);
    }
    GEMM_PROLOG_BODY
    constexpr int EPI1 = 128*(BN+12);
    constexpr int EPI2 = BN * 136;
    constexpr int EPIM = (EPI1 > EPI2) ? EPI1 : EPI2;
    constexpr int LDSN = (3*BUFSZ > EPIM) ? 3*BUFSZ : EPIM;
    __shared__ u16 lds[LDSN];
    auto stage = [&](int buf, int k0) {
        #pragma unroll
        for (int i = 0; i < CPW; ++i)
            __builtin_amdgcn_global_load_lds(
                (const __attribute__((address_space(1))) unsigned int*)(csrc[i] + k0),
                (__attribute__((address_space(3))) unsigned int*)(&lds[buf * BUFSZ + cdst[i]]),
                16, 0, 0);
    };
    const int nt = K >> 5;
    stage(0, 0);
    stage(1, 32);
    for (int t = 0; t < nt; ++t) {
        if (t + 1 < nt) waitv<CPW>();
        else            waitv<0>();
        __builtin_amdgcn_s_barrier();
        __builtin_amdgcn_sched_barrier(0);
        if (t + 2 < nt) stage((t + 2) % 3, (t + 2) << 5);
        GEMM_COMPUTE((t % 3) * BUFSZ)
    }
    int emode = mode; const float* ebias = bias; u16* eoutH = outH; u16* eoutL = outL;
    if (mode == 3) {   // fused QKV: bz selects weight slice & destination
        emode = (bz == 2) ? 2 : 1;
        ebias = bias + bz * 512;
        eoutH = (bz == 0) ? outQ : (bz == 1) ? outK : outV;
        eoutL = nullptr;
    }
    GEMM_EPILOG_SEQ
}

// ---- 256x256 tile, 16-wave (4x4), 1024 threads, BK=64, swizzled (scores) ----
__global__ __launch_bounds__(1024, 4)
void gemm256w(const u16* __restrict__ A, const u16* __restrict__ B,
              u16* __restrict__ outH,
              int K, int lda, int ldb, int ldc,
              long aStride, long bStride, long cStride, float scale)
{
    __shared__ u16 lds[2 * 32768];          // 128 KB; epilogue reuses [128][264]
    const int tid  = threadIdx.x;
    const int lane = tid & 63;
    const int wave = tid >> 6;              // 0..15
    const int wr = wave >> 2, wc = wave & 3;

    // XCD-aware swizzle (grid %8==0)
    const int gx = gridDim.x, gy = gridDim.y;
    int nwg = gx * gy * gridDim.z;
    int wg  = blockIdx.x + gx * (blockIdx.y + gy * blockIdx.z);
    int id  = (wg & 7) * (nwg >> 3) + (wg >> 3);
    const int bx = id % gx;
    const int by = (id / gx) % gy;
    const int bz = id / (gx * gy);

    const long aBase = (long)bz * aStride + (long)(bx * 256) * lda;
    const long bBase = (long)bz * bStride + (long)(by * 256) * ldb;

    const int sw     = wave & 7;
    const bool isB   = wave >= 8;
    const int srow   = lane >> 3;                       // 0..7
    const int schunk = (lane & 7) ^ (srow & 7);         // inverse-swizzled src chunk
    const u16* src_[4];
    unsigned  dst_[4];
    #pragma unroll
    for (int i = 0; i < 4; ++i) {
        int rb = sw * 8 + i * 64;
        src_[i] = (isB ? B + bBase : A + aBase)
                + (long)(rb + srow) * (isB ? ldb : lda) + schunk * 8;
        dst_[i] = (isB ? 16384 : 0) + rb * 64;
    }
    auto stage = [&](int buf, int k0) {
        #pragma unroll
        for (int i = 0; i < 4; ++i)
            __builtin_amdgcn_global_load_lds(
                (const __attribute__((address_space(1))) unsigned int*)(src_[i] + k0),
                (__attribute__((address_space(3))) unsigned int*)(&lds[buf * 32768 + dst_[i]]),
                16, 0, 0);
    };

    f32x4 acc[4][4] = {};
    const int frow = lane & 15;
    const int kq   = lane >> 4;
    const int fswz = frow & 7;

    const int nt = K >> 6;                  // BK=64
    stage(0, 0);
    stage(1, 64);
    for (int t = 0; t < nt; ++t) {
        if (t + 1 < nt) waitv<4>(); else waitv<0>();
        __builtin_amdgcn_s_barrier();
        __builtin_amdgcn_sched_barrier(0);
        const int bb = (t & 1) * 32768;
        #pragma unroll
        for (int kh = 0; kh < 2; ++kh) {
            const int ch = ((kh << 2) + kq) ^ fswz;
            bf16x8 aH[4], bH[4];
            #pragma unroll
            for (int m = 0; m < 4; ++m) {
                int rA = wr*64 + m*16 + frow;
                aH[m] = *(const bf16x8*)&lds[bb + rA*64 + ch*8];
            }
            #pragma unroll
            for (int n = 0; n < 4; ++n) {
                int rB = wc*64 + n*16 + frow;
                bH[n] = *(const bf16x8*)&lds[bb + 16384 + rB*64 + ch*8];
            }
            #pragma unroll
            for (int m = 0; m < 4; ++m)
                #pragma unroll
                for (int n = 0; n < 4; ++n)
                    acc[m][n] = __builtin_amdgcn_mfma_f32_16x16x32_bf16(aH[m], bH[n], acc[m][n], 0, 0, 0);
        }
        __builtin_amdgcn_s_barrier();
        __builtin_amdgcn_sched_barrier(0);
        if (t + 2 < nt) stage(t & 1, (t + 2) << 6);
    }

    const int rr = (lane >> 4) * 4;
    #pragma unroll
    for (int h = 0; h < 2; ++h) {
        __syncthreads();
        if ((wr >> 1) == h) {
            #pragma unroll
            for (int n = 0; n < 4; ++n) {
                int c = wc*64 + n*16 + frow;
                #pragma unroll
                for (int m = 0; m < 4; ++m)
                    #pragma unroll
                    for (int j = 0; j < 4; ++j)
                        lds[((wr & 1)*64 + m*16 + rr + j)*264 + c] = f2bf(acc[m][n][j] * scale);
            }
        }
        __syncthreads();
        for (int idx = tid; idx < 128*32; idx += 1024) {
            int row = idx >> 5, c8 = (idx & 31) * 8;
            *(bf16x8*)&outH[(long)bz*cStride + (long)(bx*256 + h*128 + row)*ldc + by*256 + c8] =
                *(bf16x8*)&lds[row*264 + c8];
        }
    }
}

// ---------------- row softmax over 2048, in-place, bf16 ----------------
__global__ __launch_bounds__(256)
void softmax_kernel(u16* __restrict__ sh)
{
    const long base = (long)blockIdx.x * 2048;
    const int tid = threadIdx.x;
    const int lane = tid & 63, wave = tid >> 6;
    u16* hp = sh + base + tid * 8;
    bf16x8 hv = *(const bf16x8*)hp;
    float s[8];
    #pragma unroll
    for (int j = 0; j < 8; ++j) s[j] = bf2f((u16)hv[j]);

    float mx = s[0];
    #pragma unroll
    for (int j = 1; j < 8; ++j) mx = fmaxf(mx, s[j]);
    #pragma unroll
    for (int off = 32; off >= 1; off >>= 1) mx = fmaxf(mx, __shfl_xor(mx, off));
    __shared__ float red[8];
    if (lane == 0) red[wave] = mx;
    __syncthreads();
    mx = fmaxf(fmaxf(red[0], red[1]), fmaxf(red[2], red[3]));

    float e[8], sum = 0.f;
    #pragma unroll
    for (int j = 0; j < 8; ++j) { e[j] = __expf(s[j] - mx); sum += e[j]; }
    #pragma unroll
    for (int off = 32; off >= 1; off >>= 1) sum += __shfl_xor(sum, off);
    if (lane == 0) red[4 + wave] = sum;
    __syncthreads();
    sum = red[4] + red[5] + red[6] + red[7];
    float inv = 1.0f / sum;

    bf16x8 ho;
    #pragma unroll
    for (int j = 0; j < 8; ++j) ho[j] = (short)f2bf(e[j] * inv);
    *(bf16x8*)hp = ho;
}

extern "C" void kernel_launch(void* const* d_in, const int* in_sizes, int n_in,
                              void* d_out, int out_size, void* d_ws, size_t ws_size,
                              hipStream_t stream)
{
    const float* x  = (const float*)d_in[0];
    const float* Wq = (const float*)d_in[1];
    const float* bq = (const float*)d_in[2];
    const float* Wk = (const float*)d_in[3];
    const float* bk = (const float*)d_in[4];
    const float* Wv = (const float*)d_in[5];
    const float* bv = (const float*)d_in[6];
    const float* Wo = (const float*)d_in[7];
    const float* bo = (const float*)d_in[8];

    char* p = (char*)d_ws;
    auto alloc = [&](size_t bytes) { char* r = p; p += (bytes + 255) & ~(size_t)255; return r; };

    const size_t XE = (size_t)ROWS * D_MODEL;     // 4,194,304
    const size_t WE = (size_t)D_MODEL * D_MODEL;  // 262,144
    const size_t SE = (size_t)BATCH * SEQ * SEQ;  // 16,777,216

    u16* xh   = (u16*)alloc(XE * 2);
    u16* xl   = (u16*)alloc(XE * 2);      // used only as att-lo (aliased below)
    u16* whh  = (u16*)alloc(3 * WE * 2);  // concat Wq,Wk,Wv (hi only)
    u16* woh  = (u16*)alloc(WE * 2);
    float* bqkv = (float*)alloc(1536 * 4);
    u16* qh   = (u16*)alloc(XE * 2);
    u16* kh   = (u16*)alloc(XE * 2);
    u16* vTh  = (u16*)alloc(XE * 2);
    u16* sh   = (u16*)alloc(SE * 2);
    // att (split) aliases x buffers — x dead after QKV projection
    u16* ath = xh;
    u16* atl = xl;

    // 1. fused prep (1 launch): x -> hi; weights -> hi; bias concat
    prep_kernel<<<5126, 256, 0, stream>>>(x, Wq, Wk, Wv, Wo, bq, bk, bv,
                                          xh, whh, woh, bqkv);

    // 2. fused QKV projection: 1-term, ring-3, BN=128 (NF=4), panel-major
    gemm3<4,1,1,1><<<dim3(768, 1, 1), 256, 0, stream>>>(xh, nullptr, whh, nullptr, bqkv,
        nullptr, nullptr, nullptr, qh, kh, vTh,
        512, 512, 512, 512, 0, (long)WE, 0, 1.0f, 3);

    // 3. scores = q@k^T * 1/sqrt(512): 256^2, 16 waves, swizzled, counted
    gemm256w<<<dim3(8, 8, 4), 1024, 0, stream>>>(qh, kh, sh,
        512, 512, 512, 2048,
        (long)SEQ * 512, (long)SEQ * 512, (long)SEQ * SEQ,
        0.044194173824159216f);

    // 4. softmax rows (bf16 in/out)
    softmax_kernel<<<ROWS, 256, 0, stream>>>(sh);

    // 5. att = p @ v: 1-term, ring-3, BN=128 (NF=4), sequential hi/lo epilogue
    gemm3<4,1,1,2><<<dim3(256, 1, 1), 256, 0, stream>>>(sh, nullptr, vTh, nullptr, nullptr,
        nullptr, ath, atl, nullptr, nullptr, nullptr,
        2048, 2048, 2048, 512,
        (long)SEQ * SEQ, (long)512 * SEQ, (long)SEQ * 512,
        1.0f, 1);

    // 6. out = att @ Wo^T + bo: 2-term (att_hi + att_lo) * Wo_hi, fp32 out
    gemm2<2,2,1><<<dim3(64, 8, 1), 256, 0, stream>>>(ath, atl, woh, nullptr, bo,
        (float*)d_out, nullptr, nullptr, 512, 512, 512, 512,
        0, 0, 0, 1.0f, 0);
}

// Round 26
// 130.762 us; speedup vs baseline: 1.0189x; 1.0189x over previous
//
#include <hip/hip_runtime.h>
#include <hip/hip_bf16.h>

#define D_MODEL 512
#define BATCH 4
#define SEQ 2048
#define ROWS (BATCH*SEQ)   // 8192

typedef unsigned short u16;
typedef short bf16x8 __attribute__((ext_vector_type(8)));
typedef float f32x4 __attribute__((ext_vector_type(4)));

__device__ __forceinline__ float bf2f(u16 u) {
    union { unsigned int i; float f; } v;
    v.i = ((unsigned int)u) << 16;
    return v.f;
}
__device__ __forceinline__ u16 f2bf(float f) {
    union { float f; unsigned int i; } v;
    v.f = f;
    unsigned int x = v.i;
    unsigned int r = (x >> 16) & 1u;
    x += 0x7fffu + r;           // round-to-nearest-even
    return (u16)(x >> 16);
}

template<int N> __device__ __forceinline__ void waitv() {
    static_assert(N==0 || N==3 || N==4 || N==5 || N==8, "unsupported vmcnt");
    if constexpr (N == 0) asm volatile("s_waitcnt vmcnt(0)" ::: "memory");
    if constexpr (N == 3) asm volatile("s_waitcnt vmcnt(3)" ::: "memory");
    if constexpr (N == 4) asm volatile("s_waitcnt vmcnt(4)" ::: "memory");
    if constexpr (N == 5) asm volatile("s_waitcnt vmcnt(5)" ::: "memory");
    if constexpr (N == 8) asm volatile("s_waitcnt vmcnt(8)" ::: "memory");
}

// ---------------- fused prep: x -> hi only; weights hi-only; bias concat ----
__global__ __launch_bounds__(256)
void prep_kernel(const float* __restrict__ x,
                 const float* __restrict__ Wq, const float* __restrict__ Wk,
                 const float* __restrict__ Wv, const float* __restrict__ Wo,
                 const float* __restrict__ bq, const float* __restrict__ bk,
                 const float* __restrict__ bv,
                 u16* __restrict__ xh,
                 u16* __restrict__ whh, u16* __restrict__ woh,
                 float* __restrict__ bqkv)
{
    const int blk = blockIdx.x;
    const int tid = threadIdx.x;
    const int WE = 262144;
    if (blk >= 5120) {
        int i = (blk - 5120) * 256 + tid;
        if (i < 1536)
            bqkv[i] = (i < 512) ? bq[i] : (i < 1024) ? bk[i - 512] : bv[i - 1024];
        return;
    }
    const float* src; u16 *dh; int i;
    if (blk < 4096) {
        src = x; dh = xh;
        i = (blk * 256 + tid) * 4;
    } else {
        int w = (blk - 4096) >> 8;
        src = (w == 0) ? Wq : (w == 1) ? Wk : (w == 2) ? Wv : Wo;
        dh  = (w < 3) ? whh + w * WE : woh;
        i = (((blk - 4096) & 255) * 256 + tid) * 4;
    }
    float4 v = *(const float4*)(src + i);
    u16 hh[4] = { f2bf(v.x), f2bf(v.y), f2bf(v.z), f2bf(v.w) };
    *(ushort4*)(dh + i) = make_ushort4(hh[0], hh[1], hh[2], hh[3]);
}

// ======== shared GEMM pieces ========
#define GEMM_PROLOG_ID                                                         \
    const int tid  = threadIdx.x;                                              \
    const int lane = tid & 63;                                                 \
    const int wave = tid >> 6;                                                 \
    const int wr = wave >> 1, wc = wave & 1;                                   \
    const int gx = gridDim.x, gy = gridDim.y;                                  \
    int nwg = gx * gy * gridDim.z;                                             \
    int wg  = blockIdx.x + gx * (blockIdx.y + gy * blockIdx.z);                \
    int id  = (wg & 7) * (nwg >> 3) + (wg >> 3);                               \
    int bx, by, bz;

#define GEMM_PROLOG_BODY                                                       \
    const long aBase = (long)bz * aStride + (long)(bx * 128) * lda;            \
    const long bBase = (long)bz * bStride + (long)(by * BN) * ldb;             \
    const u16* csrc[CPW];                                                      \
    unsigned cdst[CPW];                                                        \
    _Pragma("unroll")                                                          \
    for (int i = 0; i < CPW; ++i) {                                            \
        int c = wave + i * 4;                                                  \
        const u16* sb; int ld, lofs, row;                                      \
        if (c < AT * ACH) {                                                    \
            int t = c >> 3;                                                    \
            row = (c & 7) * 16;                                                \
            sb = (t == 0 ? Ah : Al) + aBase;                                   \
            ld = lda; lofs = t * TILE_A;                                       \
        } else {                                                               \
            int cb = c - AT * ACH;                                             \
            int t = cb / BCH;                                                  \
            row = (cb % BCH) * 16;                                             \
            sb = (t == 0 ? Bh : Bl) + bBase;                                   \
            ld = ldb; lofs = AT * TILE_A + t * TILE_B;                         \
        }                                                                      \
        csrc[i] = sb + (long)(row + (lane >> 2)) * ld + (lane & 3) * 8;        \
        cdst[i] = lofs + row * 32;                                             \
    }                                                                          \
    f32x4 acc[4][NF] = {};                                                     \
    const int frow = lane & 15;                                                \
    const int kofs = (lane >> 4) * 8;

#define GEMM_CONSTS                                                            \
    constexpr int BN     = 32 * NF;                                            \
    constexpr int TILE_A = 128 * 32;                                           \
    constexpr int TILE_B = BN * 32;                                            \
    constexpr int ACH    = 8;                                                  \
    constexpr int BCH    = BN / 16;                                            \
    constexpr int NCH    = AT*ACH + BT*BCH;                                    \
    constexpr int CPW    = NCH / 4;                                            \
    constexpr int BUFSZ  = AT*TILE_A + BT*TILE_B;

#define GEMM_COMPUTE(bb_)                                                      \
    {                                                                          \
        const int bb = (bb_);                                                  \
        bf16x8 aH[4], aL[4], bH[NF], bL[NF];                                   \
        _Pragma("unroll")                                                      \
        for (int m = 0; m < 4; ++m) {                                          \
            int rA = wr*64 + m*16 + frow;                                      \
            aH[m] = *(const bf16x8*)&lds[bb + rA*32 + kofs];                   \
            if constexpr (AT == 2)                                             \
                aL[m] = *(const bf16x8*)&lds[bb + TILE_A + rA*32 + kofs];      \
        }                                                                      \
        _Pragma("unroll")                                                      \
        for (int n = 0; n < NF; ++n) {                                         \
            int rB = wc*(NF*16) + n*16 + frow;                                 \
            bH[n] = *(const bf16x8*)&lds[bb + AT*TILE_A + rB*32 + kofs];       \
            if constexpr (BT == 2)                                             \
                bL[n] = *(const bf16x8*)&lds[bb + AT*TILE_A + TILE_B + rB*32 + kofs]; \
        }                                                                      \
        _Pragma("unroll")                                                      \
        for (int m = 0; m < 4; ++m)                                            \
            _Pragma("unroll")                                                  \
            for (int n = 0; n < NF; ++n) {                                     \
                acc[m][n] = __builtin_amdgcn_mfma_f32_16x16x32_bf16(aH[m], bH[n], acc[m][n], 0, 0, 0); \
                if constexpr (BT == 2)                                         \
                    acc[m][n] = __builtin_amdgcn_mfma_f32_16x16x32_bf16(aH[m], bL[n], acc[m][n], 0, 0, 0); \
                if constexpr (AT == 2)                                         \
                    acc[m][n] = __builtin_amdgcn_mfma_f32_16x16x32_bf16(aL[m], bH[n], acc[m][n], 0, 0, 0); \
            }                                                                  \
    }

// Double-buffer staged epilogue (gemm2: hi+lo side-by-side buffers).
#define GEMM_EPILOG_STAGED                                                     \
    {                                                                          \
    const int rr = (lane >> 4) * 4;                                            \
    __syncthreads();                                                           \
    if (emode == 0) {                                                          \
        float* ldsF = (float*)lds;                                             \
        _Pragma("unroll")                                                      \
        for (int n = 0; n < NF; ++n) {                                         \
            int c = wc*(NF*16) + n*16 + frow;                                  \
            float bv_ = ebias ? ebias[by*BN + c] : 0.0f;                       \
            _Pragma("unroll")                                                  \
            for (int m = 0; m < 4; ++m)                                        \
                _Pragma("unroll")                                              \
                for (int j = 0; j < 4; ++j)                                    \
                    ldsF[(wr*64 + m*16 + rr + j)*(BN+4) + c] = acc[m][n][j]*scale + bv_; \
        }                                                                      \
        __syncthreads();                                                       \
        for (int idx = tid; idx < 128*(BN/4); idx += 256) {                    \
            int row = idx / (BN/4), c4 = (idx % (BN/4)) * 4;                   \
            *(float4*)&outF[(long)bz*cStride + (long)(bx*128+row)*ldc + by*BN + c4] = \
                *(float4*)&ldsF[row*(BN+4) + c4];                              \
        }                                                                      \
    } else {                                                                   \
        u16* ldsH = (u16*)lds;                                                 \
        u16* ldsL = (u16*)lds + 128*(BN+12);                                   \
        _Pragma("unroll")                                                      \
        for (int n = 0; n < NF; ++n) {                                         \
            int c = wc*(NF*16) + n*16 + frow;                                  \
            float bv_ = ebias ? ebias[by*BN + c] : 0.0f;                       \
            _Pragma("unroll")                                                  \
            for (int m = 0; m < 4; ++m)                                        \
                _Pragma("unroll")                                              \
                for (int j = 0; j < 4; ++j) {                                  \
                    int r = wr*64 + m*16 + rr + j;                             \
                    float val = acc[m][n][j]*scale + bv_;                      \
                    u16 h = f2bf(val);                                         \
                    ldsH[r*(BN+12) + c] = h;                                   \
                    if (eoutL) ldsL[r*(BN+12) + c] = f2bf(val - bf2f(h));      \
                }                                                              \
        }                                                                      \
        __syncthreads();                                                       \
        for (int idx = tid; idx < 128*(BN/8); idx += 256) {                    \
            int row = idx / (BN/8), c8 = (idx % (BN/8)) * 8;                   \
            long o = (long)bz*cStride + (long)(bx*128+row)*ldc + by*BN + c8;   \
            *(bf16x8*)&eoutH[o] = *(bf16x8*)&ldsH[row*(BN+12) + c8];           \
            if (eoutL) *(bf16x8*)&eoutL[o] = *(bf16x8*)&ldsL[row*(BN+12) + c8]; \
        }                                                                      \
    }                                                                          \
    }

// Sequential single-buffer staged epilogue (gemm3): hi pass then lo pass
// through ONE [128][BN+12] buffer -> LDS stays at 3*BUFSZ (occupancy-safe).
#define GEMM_EPILOG_SEQ                                                        \
    {                                                                          \
    const int rr = (lane >> 4) * 4;                                            \
    if (emode == 2) {                                                          \
        u16* ldsT = (u16*)lds;   /* [BN][136]: transposed tile */              \
        __syncthreads();                                                       \
        _Pragma("unroll")                                                      \
        for (int n = 0; n < NF; ++n) {                                         \
            int c = wc*(NF*16) + n*16 + frow;                                  \
            float bv_ = ebias ? ebias[by*BN + c] : 0.0f;                       \
            _Pragma("unroll")                                                  \
            for (int m = 0; m < 4; ++m)                                        \
                _Pragma("unroll")                                              \
                for (int j = 0; j < 4; ++j)                                    \
                    ldsT[c*136 + (wr*64 + m*16 + rr + j)] = f2bf(acc[m][n][j]*scale + bv_); \
        }                                                                      \
        __syncthreads();                                                       \
        int b = bx >> 4, mrowBase = (bx & 15) * 128;                           \
        for (int idx = tid; idx < BN*16; idx += 256) {                         \
            int crow = idx >> 4, r8 = (idx & 15) * 8;                          \
            *(bf16x8*)&eoutH[(long)b*1048576 + (long)(by*BN + crow)*2048 + mrowBase + r8] = \
                *(bf16x8*)&ldsT[crow*136 + r8];                                \
        }                                                                      \
    } else {                                                                   \
        u16* ldsH = (u16*)lds;                                                 \
        const int parts = eoutL ? 2 : 1;                                       \
        for (int part = 0; part < parts; ++part) {                             \
            u16* dstG = part ? eoutL : eoutH;                                  \
            __syncthreads();                                                   \
            _Pragma("unroll")                                                  \
            for (int n = 0; n < NF; ++n) {                                     \
                int c = wc*(NF*16) + n*16 + frow;                              \
                float bv_ = ebias ? ebias[by*BN + c] : 0.0f;                   \
                _Pragma("unroll")                                              \
                for (int m = 0; m < 4; ++m)                                    \
                    _Pragma("unroll")                                          \
                    for (int j = 0; j < 4; ++j) {                              \
                        int r = wr*64 + m*16 + rr + j;                         \
                        float val = acc[m][n][j]*scale + bv_;                  \
                        u16 h = f2bf(val);                                     \
                        ldsH[r*(BN+12) + c] = part ? f2bf(val - bf2f(h)) : h;  \
                    }                                                          \
            }                                                                  \
            __syncthreads();                                                   \
            for (int idx = tid; idx < 128*(BN/8); idx += 256) {                \
                int row = idx / (BN/8), c8 = (idx % (BN/8)) * 8;               \
                *(bf16x8*)&dstG[(long)bz*cStride + (long)(bx*128+row)*ldc + by*BN + c8] = \
                    *(bf16x8*)&ldsH[row*(BN+12) + c8];                         \
            }                                                                  \
        }                                                                      \
    }                                                                          \
    }

// ---- 2-buffer variant (final projection) ----
template<int NF, int AT, int BT>
__global__ __launch_bounds__(256)
void gemm2(const u16* __restrict__ Ah, const u16* __restrict__ Al,
           const u16* __restrict__ Bh, const u16* __restrict__ Bl,
           const float* __restrict__ bias,
           float* __restrict__ outF, u16* __restrict__ outH, u16* __restrict__ outL,
           int K, int lda, int ldb, int ldc,
           long aStride, long bStride, long cStride,
           float scale, int mode)
{
    GEMM_CONSTS
    GEMM_PROLOG_ID
    bx = id % gx;
    by = (id / gx) % gy;
    bz = id / (gx * gy);
    GEMM_PROLOG_BODY
    constexpr int EPI1 = 2 * 128*(BN+12);
    constexpr int EPI0 = 256*(BN+4);
    constexpr int L1   = (2*BUFSZ > EPI1) ? 2*BUFSZ : EPI1;
    constexpr int LDSN = (L1 > EPI0) ? L1 : EPI0;
    __shared__ u16 lds[LDSN];
    auto stage = [&](int buf, int k0) {
        #pragma unroll
        for (int i = 0; i < CPW; ++i)
            __builtin_amdgcn_global_load_lds(
                (const __attribute__((address_space(1))) unsigned int*)(csrc[i] + k0),
                (__attribute__((address_space(3))) unsigned int*)(&lds[buf * BUFSZ + cdst[i]]),
                16, 0, 0);
    };
    const int nt = K >> 5;
    stage(0, 0);
    __syncthreads();
    int cur = 0;
    for (int t = 0; t < nt; ++t) {
        if (t + 1 < nt) stage(cur ^ 1, (t + 1) << 5);
        GEMM_COMPUTE(cur * BUFSZ)
        __syncthreads();
        cur ^= 1;
    }
    int emode = mode; const float* ebias = bias; u16* eoutH = outH; u16* eoutL = outL;
    GEMM_EPILOG_STAGED
}

// ---- ring-3 counted-vmcnt variant ----
// DEC=1 (QKV fused): inner=id%(3*(512/BN)) -> (by, bz weight-slice), bx outer.
template<int NF, int AT, int BT, int DEC = 0>
__global__ __launch_bounds__(256)
void gemm3(const u16* __restrict__ Ah, const u16* __restrict__ Al,
           const u16* __restrict__ Bh, const u16* __restrict__ Bl,
           const float* __restrict__ bias,
           float* __restrict__ outF, u16* __restrict__ outH, u16* __restrict__ outL,
           u16* __restrict__ outQ, u16* __restrict__ outK, u16* __restrict__ outV,
           int K, int lda, int ldb, int ldc,
           long aStride, long bStride, long cStride,
           float scale, int mode)
{
    GEMM_CONSTS
    GEMM_PROLOG_ID
    if constexpr (DEC == 1) {
        constexpr int NBY = 512 / BN;
        constexpr int INN = 3 * NBY;
        int inner = id % INN;
        by = inner % NBY;
        bz = inner / NBY;
        bx = id / INN;
    } else {
        bx = id % gx;
        by = (id / gx) % gy;
        bz = id / (gx * gy);
    }
    GEMM_PROLOG_BODY
    constexpr int EPI1 = 128*(BN+12);
    constexpr int EPI2 = BN * 136;
    constexpr int EPIM = (EPI1 > EPI2) ? EPI1 : EPI2;
    constexpr int LDSN = (3*BUFSZ > EPIM) ? 3*BUFSZ : EPIM;
    __shared__ u16 lds[LDSN];
    auto stage = [&](int buf, int k0) {
        #pragma unroll
        for (int i = 0; i < CPW; ++i)
            __builtin_amdgcn_global_load_lds(
                (const __attribute__((address_space(1))) unsigned int*)(csrc[i] + k0),
                (__attribute__((address_space(3))) unsigned int*)(&lds[buf * BUFSZ + cdst[i]]),
                16, 0, 0);
    };
    const int nt = K >> 5;
    stage(0, 0);
    stage(1, 32);
    for (int t = 0; t < nt; ++t) {
        if (t + 1 < nt) waitv<CPW>();
        else            waitv<0>();
        __builtin_amdgcn_s_barrier();
        __builtin_amdgcn_sched_barrier(0);
        if (t + 2 < nt) stage((t + 2) % 3, (t + 2) << 5);
        GEMM_COMPUTE((t % 3) * BUFSZ)
    }
    int emode = mode; const float* ebias = bias; u16* eoutH = outH; u16* eoutL = outL;
    if (mode == 3) {   // fused QKV: bz selects weight slice & destination
        emode = (bz == 2) ? 2 : 1;
        ebias = bias + bz * 512;
        eoutH = (bz == 0) ? outQ : (bz == 1) ? outK : outV;
        eoutL = nullptr;
    }
    GEMM_EPILOG_SEQ
}

// ---- 256x256 tile, 16-wave (4x4), 1024 threads, BK=64, swizzled (scores) ----
__global__ __launch_bounds__(1024, 4)
void gemm256w(const u16* __restrict__ A, const u16* __restrict__ B,
              u16* __restrict__ outH,
              int K, int lda, int ldb, int ldc,
              long aStride, long bStride, long cStride, float scale)
{
    __shared__ u16 lds[2 * 32768];          // 128 KB; epilogue reuses [128][264]
    const int tid  = threadIdx.x;
    const int lane = tid & 63;
    const int wave = tid >> 6;              // 0..15
    const int wr = wave >> 2, wc = wave & 3;

    // XCD-aware swizzle (grid %8==0)
    const int gx = gridDim.x, gy = gridDim.y;
    int nwg = gx * gy * gridDim.z;
    int wg  = blockIdx.x + gx * (blockIdx.y + gy * blockIdx.z);
    int id  = (wg & 7) * (nwg >> 3) + (wg >> 3);
    const int bx = id % gx;
    const int by = (id / gx) % gy;
    const int bz = id / (gx * gy);

    const long aBase = (long)bz * aStride + (long)(bx * 256) * lda;
    const long bBase = (long)bz * bStride + (long)(by * 256) * ldb;

    const int sw     = wave & 7;
    const bool isB   = wave >= 8;
    const int srow   = lane >> 3;                       // 0..7
    const int schunk = (lane & 7) ^ (srow & 7);         // inverse-swizzled src chunk
    const u16* src_[4];
    unsigned  dst_[4];
    #pragma unroll
    for (int i = 0; i < 4; ++i) {
        int rb = sw * 8 + i * 64;
        src_[i] = (isB ? B + bBase : A + aBase)
                + (long)(rb + srow) * (isB ? ldb : lda) + schunk * 8;
        dst_[i] = (isB ? 16384 : 0) + rb * 64;
    }
    auto stage = [&](int buf, int k0) {
        #pragma unroll
        for (int i = 0; i < 4; ++i)
            __builtin_amdgcn_global_load_lds(
                (const __attribute__((address_space(1))) unsigned int*)(src_[i] + k0),
                (__attribute__((address_space(3))) unsigned int*)(&lds[buf * 32768 + dst_[i]]),
                16, 0, 0);
    };

    f32x4 acc[4][4] = {};
    const int frow = lane & 15;
    const int kq   = lane >> 4;
    const int fswz = frow & 7;

    const int nt = K >> 6;                  // BK=64
    stage(0, 0);
    stage(1, 64);
    for (int t = 0; t < nt; ++t) {
        if (t + 1 < nt) waitv<4>(); else waitv<0>();
        __builtin_amdgcn_s_barrier();
        __builtin_amdgcn_sched_barrier(0);
        const int bb = (t & 1) * 32768;
        #pragma unroll
        for (int kh = 0; kh < 2; ++kh) {
            const int ch = ((kh << 2) + kq) ^ fswz;
            bf16x8 aH[4], bH[4];
            #pragma unroll
            for (int m = 0; m < 4; ++m) {
                int rA = wr*64 + m*16 + frow;
                aH[m] = *(const bf16x8*)&lds[bb + rA*64 + ch*8];
            }
            #pragma unroll
            for (int n = 0; n < 4; ++n) {
                int rB = wc*64 + n*16 + frow;
                bH[n] = *(const bf16x8*)&lds[bb + 16384 + rB*64 + ch*8];
            }
            #pragma unroll
            for (int m = 0; m < 4; ++m)
                #pragma unroll
                for (int n = 0; n < 4; ++n)
                    acc[m][n] = __builtin_amdgcn_mfma_f32_16x16x32_bf16(aH[m], bH[n], acc[m][n], 0, 0, 0);
        }
        __builtin_amdgcn_s_barrier();
        __builtin_amdgcn_sched_barrier(0);
        if (t + 2 < nt) stage(t & 1, (t + 2) << 6);
    }

    const int rr = (lane >> 4) * 4;
    #pragma unroll
    for (int h = 0; h < 2; ++h) {
        __syncthreads();
        if ((wr >> 1) == h) {
            #pragma unroll
            for (int n = 0; n < 4; ++n) {
                int c = wc*64 + n*16 + frow;
                #pragma unroll
                for (int m = 0; m < 4; ++m)
                    #pragma unroll
                    for (int j = 0; j < 4; ++j)
                        lds[((wr & 1)*64 + m*16 + rr + j)*264 + c] = f2bf(acc[m][n][j] * scale);
            }
        }
        __syncthreads();
        for (int idx = tid; idx < 128*32; idx += 1024) {
            int row = idx >> 5, c8 = (idx & 31) * 8;
            *(bf16x8*)&outH[(long)bz*cStride + (long)(bx*256 + h*128 + row)*ldc + by*256 + c8] =
                *(bf16x8*)&lds[row*264 + c8];
        }
    }
}

// ---------------- row softmax over 2048, in-place, bf16 ----------------
__global__ __launch_bounds__(256)
void softmax_kernel(u16* __restrict__ sh)
{
    const long base = (long)blockIdx.x * 2048;
    const int tid = threadIdx.x;
    const int lane = tid & 63, wave = tid >> 6;
    u16* hp = sh + base + tid * 8;
    bf16x8 hv = *(const bf16x8*)hp;
    float s[8];
    #pragma unroll
    for (int j = 0; j < 8; ++j) s[j] = bf2f((u16)hv[j]);

    float mx = s[0];
    #pragma unroll
    for (int j = 1; j < 8; ++j) mx = fmaxf(mx, s[j]);
    #pragma unroll
    for (int off = 32; off >= 1; off >>= 1) mx = fmaxf(mx, __shfl_xor(mx, off));
    __shared__ float red[8];
    if (lane == 0) red[wave] = mx;
    __syncthreads();
    mx = fmaxf(fmaxf(red[0], red[1]), fmaxf(red[2], red[3]));

    float e[8], sum = 0.f;
    #pragma unroll
    for (int j = 0; j < 8; ++j) { e[j] = __expf(s[j] - mx); sum += e[j]; }
    #pragma unroll
    for (int off = 32; off >= 1; off >>= 1) sum += __shfl_xor(sum, off);
    if (lane == 0) red[4 + wave] = sum;
    __syncthreads();
    sum = red[4] + red[5] + red[6] + red[7];
    float inv = 1.0f / sum;

    bf16x8 ho;
    #pragma unroll
    for (int j = 0; j < 8; ++j) ho[j] = (short)f2bf(e[j] * inv);
    *(bf16x8*)hp = ho;
}

extern "C" void kernel_launch(void* const* d_in, const int* in_sizes, int n_in,
                              void* d_out, int out_size, void* d_ws, size_t ws_size,
                              hipStream_t stream)
{
    const float* x  = (const float*)d_in[0];
    const float* Wq = (const float*)d_in[1];
    const float* bq = (const float*)d_in[2];
    const float* Wk = (const float*)d_in[3];
    const float* bk = (const float*)d_in[4];
    const float* Wv = (const float*)d_in[5];
    const float* bv = (const float*)d_in[6];
    const float* Wo = (const float*)d_in[7];
    const float* bo = (const float*)d_in[8];

    char* p = (char*)d_ws;
    auto alloc = [&](size_t bytes) { char* r = p; p += (bytes + 255) & ~(size_t)255; return r; };

    const size_t XE = (size_t)ROWS * D_MODEL;     // 4,194,304
    const size_t WE = (size_t)D_MODEL * D_MODEL;  // 262,144
    const size_t SE = (size_t)BATCH * SEQ * SEQ;  // 16,777,216

    u16* xh   = (u16*)alloc(XE * 2);
    u16* xl   = (u16*)alloc(XE * 2);      // used only as att-lo (aliased below)
    u16* whh  = (u16*)alloc(3 * WE * 2);  // concat Wq,Wk,Wv (hi only)
    u16* woh  = (u16*)alloc(WE * 2);
    float* bqkv = (float*)alloc(1536 * 4);
    u16* qh   = (u16*)alloc(XE * 2);
    u16* kh   = (u16*)alloc(XE * 2);
    u16* vTh  = (u16*)alloc(XE * 2);
    u16* sh   = (u16*)alloc(SE * 2);
    // att (split) aliases x buffers — x dead after QKV projection
    u16* ath = xh;
    u16* atl = xl;

    // 1. fused prep (1 launch): x -> hi; weights -> hi; bias concat
    prep_kernel<<<5126, 256, 0, stream>>>(x, Wq, Wk, Wv, Wo, bq, bk, bv,
                                          xh, whh, woh, bqkv);

    // 2. fused QKV projection: 1-term, ring-3, BN=128 (NF=4), panel-major
    gemm3<4,1,1,1><<<dim3(768, 1, 1), 256, 0, stream>>>(xh, nullptr, whh, nullptr, bqkv,
        nullptr, nullptr, nullptr, qh, kh, vTh,
        512, 512, 512, 512, 0, (long)WE, 0, 1.0f, 3);

    // 3. scores = q@k^T * 1/sqrt(512): 256^2, 16 waves, swizzled, counted
    gemm256w<<<dim3(8, 8, 4), 1024, 0, stream>>>(qh, kh, sh,
        512, 512, 512, 2048,
        (long)SEQ * 512, (long)SEQ * 512, (long)SEQ * SEQ,
        0.044194173824159216f);

    // 4. softmax rows (bf16 in/out)
    softmax_kernel<<<ROWS, 256, 0, stream>>>(sh);

    // 5. att = p @ v: 1-term, ring-3, NF=2 (512 blocks = 2/CU), seq hi/lo epilogue
    gemm3<2,1,1><<<dim3(16, 8, 4), 256, 0, stream>>>(sh, nullptr, vTh, nullptr, nullptr,
        nullptr, ath, atl, nullptr, nullptr, nullptr,
        2048, 2048, 2048, 512,
        (long)SEQ * SEQ, (long)512 * SEQ, (long)SEQ * 512,
        1.0f, 1);

    // 6. out = att @ Wo^T + bo: 2-term (att_hi + att_lo) * Wo_hi, fp32 out
    gemm2<2,2,1><<<dim3(64, 8, 1), 256, 0, stream>>>(ath, atl, woh, nullptr, bo,
        (float*)d_out, nullptr, nullptr, 512, 512, 512, 512,
        0, 0, 0, 1.0f, 0);
}

// Round 27
// 126.622 us; speedup vs baseline: 1.0522x; 1.0327x over previous
//
#include <hip/hip_runtime.h>
#include <hip/hip_bf16.h>

#define D_MODEL 512
#define BATCH 4
#define SEQ 2048
#define ROWS (BATCH*SEQ)   // 8192

typedef unsigned short u16;
typedef short bf16x8 __attribute__((ext_vector_type(8)));
typedef float f32x4 __attribute__((ext_vector_type(4)));

__device__ __forceinline__ float bf2f(u16 u) {
    union { unsigned int i; float f; } v;
    v.i = ((unsigned int)u) << 16;
    return v.f;
}
__device__ __forceinline__ u16 f2bf(float f) {
    union { float f; unsigned int i; } v;
    v.f = f;
    unsigned int x = v.i;
    unsigned int r = (x >> 16) & 1u;
    x += 0x7fffu + r;           // round-to-nearest-even
    return (u16)(x >> 16);
}

template<int N> __device__ __forceinline__ void waitv() {
    static_assert(N==0 || N==3 || N==4 || N==5 || N==8, "unsupported vmcnt");
    if constexpr (N == 0) asm volatile("s_waitcnt vmcnt(0)" ::: "memory");
    if constexpr (N == 3) asm volatile("s_waitcnt vmcnt(3)" ::: "memory");
    if constexpr (N == 4) asm volatile("s_waitcnt vmcnt(4)" ::: "memory");
    if constexpr (N == 5) asm volatile("s_waitcnt vmcnt(5)" ::: "memory");
    if constexpr (N == 8) asm volatile("s_waitcnt vmcnt(8)" ::: "memory");
}

// ---------------- fused prep: x -> hi only; weights hi-only; bias concat ----
__global__ __launch_bounds__(256)
void prep_kernel(const float* __restrict__ x,
                 const float* __restrict__ Wq, const float* __restrict__ Wk,
                 const float* __restrict__ Wv, const float* __restrict__ Wo,
                 const float* __restrict__ bq, const float* __restrict__ bk,
                 const float* __restrict__ bv,
                 u16* __restrict__ xh,
                 u16* __restrict__ whh, u16* __restrict__ woh,
                 float* __restrict__ bqkv)
{
    const int blk = blockIdx.x;
    const int tid = threadIdx.x;
    const int WE = 262144;
    if (blk >= 5120) {
        int i = (blk - 5120) * 256 + tid;
        if (i < 1536)
            bqkv[i] = (i < 512) ? bq[i] : (i < 1024) ? bk[i - 512] : bv[i - 1024];
        return;
    }
    const float* src; u16 *dh; int i;
    if (blk < 4096) {
        src = x; dh = xh;
        i = (blk * 256 + tid) * 4;
    } else {
        int w = (blk - 4096) >> 8;
        src = (w == 0) ? Wq : (w == 1) ? Wk : (w == 2) ? Wv : Wo;
        dh  = (w < 3) ? whh + w * WE : woh;
        i = (((blk - 4096) & 255) * 256 + tid) * 4;
    }
    float4 v = *(const float4*)(src + i);
    u16 hh[4] = { f2bf(v.x), f2bf(v.y), f2bf(v.z), f2bf(v.w) };
    *(ushort4*)(dh + i) = make_ushort4(hh[0], hh[1], hh[2], hh[3]);
}

// ======== shared GEMM pieces ========
#define GEMM_PROLOG_ID                                                         \
    const int tid  = threadIdx.x;                                              \
    const int lane = tid & 63;                                                 \
    const int wave = tid >> 6;                                                 \
    const int wr = wave >> 1, wc = wave & 1;                                   \
    const int gx = gridDim.x, gy = gridDim.y;                                  \
    int nwg = gx * gy * gridDim.z;                                             \
    int wg  = blockIdx.x + gx * (blockIdx.y + gy * blockIdx.z);                \
    int id  = (wg & 7) * (nwg >> 3) + (wg >> 3);                               \
    int bx, by, bz;

#define GEMM_PROLOG_BODY                                                       \
    const long aBase = (long)bz * aStride + (long)(bx * 128) * lda;            \
    const long bBase = (long)bz * bStride + (long)(by * BN) * ldb;             \
    const u16* csrc[CPW];                                                      \
    unsigned cdst[CPW];                                                        \
    _Pragma("unroll")                                                          \
    for (int i = 0; i < CPW; ++i) {                                            \
        int c = wave + i * 4;                                                  \
        const u16* sb; int ld, lofs, row;                                      \
        if (c < AT * ACH) {                                                    \
            int t = c >> 3;                                                    \
            row = (c & 7) * 16;                                                \
            sb = (t == 0 ? Ah : Al) + aBase;                                   \
            ld = lda; lofs = t * TILE_A;                                       \
        } else {                                                               \
            int cb = c - AT * ACH;                                             \
            int t = cb / BCH;                                                  \
            row = (cb % BCH) * 16;                                             \
            sb = (t == 0 ? Bh : Bl) + bBase;                                   \
            ld = ldb; lofs = AT * TILE_A + t * TILE_B;                         \
        }                                                                      \
        csrc[i] = sb + (long)(row + (lane >> 2)) * ld + (lane & 3) * 8;        \
        cdst[i] = lofs + row * 32;                                             \
    }                                                                          \
    f32x4 acc[4][NF] = {};                                                     \
    const int frow = lane & 15;                                                \
    const int kofs = (lane >> 4) * 8;

#define GEMM_CONSTS                                                            \
    constexpr int BN     = 32 * NF;                                            \
    constexpr int TILE_A = 128 * 32;                                           \
    constexpr int TILE_B = BN * 32;                                            \
    constexpr int ACH    = 8;                                                  \
    constexpr int BCH    = BN / 16;                                            \
    constexpr int NCH    = AT*ACH + BT*BCH;                                    \
    constexpr int CPW    = NCH / 4;                                            \
    constexpr int BUFSZ  = AT*TILE_A + BT*TILE_B;

#define GEMM_COMPUTE(bb_)                                                      \
    {                                                                          \
        const int bb = (bb_);                                                  \
        bf16x8 aH[4], aL[4], bH[NF], bL[NF];                                   \
        _Pragma("unroll")                                                      \
        for (int m = 0; m < 4; ++m) {                                          \
            int rA = wr*64 + m*16 + frow;                                      \
            aH[m] = *(const bf16x8*)&lds[bb + rA*32 + kofs];                   \
            if constexpr (AT == 2)                                             \
                aL[m] = *(const bf16x8*)&lds[bb + TILE_A + rA*32 + kofs];      \
        }                                                                      \
        _Pragma("unroll")                                                      \
        for (int n = 0; n < NF; ++n) {                                         \
            int rB = wc*(NF*16) + n*16 + frow;                                 \
            bH[n] = *(const bf16x8*)&lds[bb + AT*TILE_A + rB*32 + kofs];       \
            if constexpr (BT == 2)                                             \
                bL[n] = *(const bf16x8*)&lds[bb + AT*TILE_A + TILE_B + rB*32 + kofs]; \
        }                                                                      \
        _Pragma("unroll")                                                      \
        for (int m = 0; m < 4; ++m)                                            \
            _Pragma("unroll")                                                  \
            for (int n = 0; n < NF; ++n) {                                     \
                acc[m][n] = __builtin_amdgcn_mfma_f32_16x16x32_bf16(aH[m], bH[n], acc[m][n], 0, 0, 0); \
                if constexpr (BT == 2)                                         \
                    acc[m][n] = __builtin_amdgcn_mfma_f32_16x16x32_bf16(aH[m], bL[n], acc[m][n], 0, 0, 0); \
                if constexpr (AT == 2)                                         \
                    acc[m][n] = __builtin_amdgcn_mfma_f32_16x16x32_bf16(aL[m], bH[n], acc[m][n], 0, 0, 0); \
            }                                                                  \
    }

// Staged epilogue (uses emode/ebias/eoutH/eoutL, set per-kernel before use).
#define GEMM_EPILOG_STAGED                                                     \
    {                                                                          \
    const int rr = (lane >> 4) * 4;                                            \
    __syncthreads();                                                           \
    if (emode == 0) {                                                          \
        float* ldsF = (float*)lds;                                             \
        _Pragma("unroll")                                                      \
        for (int n = 0; n < NF; ++n) {                                         \
            int c = wc*(NF*16) + n*16 + frow;                                  \
            float bv_ = ebias ? ebias[by*BN + c] : 0.0f;                       \
            _Pragma("unroll")                                                  \
            for (int m = 0; m < 4; ++m)                                        \
                _Pragma("unroll")                                              \
                for (int j = 0; j < 4; ++j)                                    \
                    ldsF[(wr*64 + m*16 + rr + j)*(BN+4) + c] = acc[m][n][j]*scale + bv_; \
        }                                                                      \
        __syncthreads();                                                       \
        for (int idx = tid; idx < 128*(BN/4); idx += 256) {                    \
            int row = idx / (BN/4), c4 = (idx % (BN/4)) * 4;                   \
            *(float4*)&outF[(long)bz*cStride + (long)(bx*128+row)*ldc + by*BN + c4] = \
                *(float4*)&ldsF[row*(BN+4) + c4];                              \
        }                                                                      \
    } else if (emode == 1) {                                                   \
        u16* ldsH = (u16*)lds;                                                 \
        u16* ldsL = (u16*)lds + 128*(BN+12);                                   \
        _Pragma("unroll")                                                      \
        for (int n = 0; n < NF; ++n) {                                         \
            int c = wc*(NF*16) + n*16 + frow;                                  \
            float bv_ = ebias ? ebias[by*BN + c] : 0.0f;                       \
            _Pragma("unroll")                                                  \
            for (int m = 0; m < 4; ++m)                                        \
                _Pragma("unroll")                                              \
                for (int j = 0; j < 4; ++j) {                                  \
                    int r = wr*64 + m*16 + rr + j;                             \
                    float val = acc[m][n][j]*scale + bv_;                      \
                    u16 h = f2bf(val);                                         \
                    ldsH[r*(BN+12) + c] = h;                                   \
                    if (eoutL) ldsL[r*(BN+12) + c] = f2bf(val - bf2f(h));      \
                }                                                              \
        }                                                                      \
        __syncthreads();                                                       \
        for (int idx = tid; idx < 128*(BN/8); idx += 256) {                    \
            int row = idx / (BN/8), c8 = (idx % (BN/8)) * 8;                   \
            long o = (long)bz*cStride + (long)(bx*128+row)*ldc + by*BN + c8;   \
            *(bf16x8*)&eoutH[o] = *(bf16x8*)&ldsH[row*(BN+12) + c8];           \
            if (eoutL) *(bf16x8*)&eoutL[o] = *(bf16x8*)&ldsL[row*(BN+12) + c8]; \
        }                                                                      \
    } else {                                                                   \
        u16* ldsT = (u16*)lds;   /* [BN][136]: transposed tile */              \
        _Pragma("unroll")                                                      \
        for (int n = 0; n < NF; ++n) {                                         \
            int c = wc*(NF*16) + n*16 + frow;                                  \
            float bv_ = ebias ? ebias[by*BN + c] : 0.0f;                       \
            _Pragma("unroll")                                                  \
            for (int m = 0; m < 4; ++m)                                        \
                _Pragma("unroll")                                              \
                for (int j = 0; j < 4; ++j)                                    \
                    ldsT[c*136 + (wr*64 + m*16 + rr + j)] = f2bf(acc[m][n][j]*scale + bv_); \
        }                                                                      \
        __syncthreads();                                                       \
        int b = bx >> 4, mrowBase = (bx & 15) * 128;                           \
        for (int idx = tid; idx < BN*16; idx += 256) {                         \
            int crow = idx >> 4, r8 = (idx & 15) * 8;                          \
            *(bf16x8*)&eoutH[(long)b*1048576 + (long)(by*BN + crow)*2048 + mrowBase + r8] = \
                *(bf16x8*)&ldsT[crow*136 + r8];                                \
        }                                                                      \
    }                                                                          \
    }

// ---- 2-buffer variant (final projection) ----
template<int NF, int AT, int BT>
__global__ __launch_bounds__(256)
void gemm2(const u16* __restrict__ Ah, const u16* __restrict__ Al,
           const u16* __restrict__ Bh, const u16* __restrict__ Bl,
           const float* __restrict__ bias,
           float* __restrict__ outF, u16* __restrict__ outH, u16* __restrict__ outL,
           int K, int lda, int ldb, int ldc,
           long aStride, long bStride, long cStride,
           float scale, int mode)
{
    GEMM_CONSTS
    GEMM_PROLOG_ID
    bx = id % gx;
    by = (id / gx) % gy;
    bz = id / (gx * gy);
    GEMM_PROLOG_BODY
    constexpr int EPI1 = 2 * 128*(BN+12);
    constexpr int EPI0 = 256*(BN+4);
    constexpr int L1   = (2*BUFSZ > EPI1) ? 2*BUFSZ : EPI1;
    constexpr int LDSN = (L1 > EPI0) ? L1 : EPI0;
    __shared__ u16 lds[LDSN];
    auto stage = [&](int buf, int k0) {
        #pragma unroll
        for (int i = 0; i < CPW; ++i)
            __builtin_amdgcn_global_load_lds(
                (const __attribute__((address_space(1))) unsigned int*)(csrc[i] + k0),
                (__attribute__((address_space(3))) unsigned int*)(&lds[buf * BUFSZ + cdst[i]]),
                16, 0, 0);
    };
    const int nt = K >> 5;
    stage(0, 0);
    __syncthreads();
    int cur = 0;
    for (int t = 0; t < nt; ++t) {
        if (t + 1 < nt) stage(cur ^ 1, (t + 1) << 5);
        GEMM_COMPUTE(cur * BUFSZ)
        __syncthreads();
        cur ^= 1;
    }
    int emode = mode; const float* ebias = bias; u16* eoutH = outH; u16* eoutL = outL;
    GEMM_EPILOG_STAGED
}

// ---- ring-3 counted-vmcnt variant ----
// DEC=1 (QKV fused): inner=id%(3*(512/BN)) -> (by, bz weight-slice), bx outer.
// ELO: epilogue LDS sized for hi+lo (1) or hi-only (0).
template<int NF, int AT, int BT, int DEC = 0, int ELO = 1>
__global__ __launch_bounds__(256)
void gemm3(const u16* __restrict__ Ah, const u16* __restrict__ Al,
           const u16* __restrict__ Bh, const u16* __restrict__ Bl,
           const float* __restrict__ bias,
           float* __restrict__ outF, u16* __restrict__ outH, u16* __restrict__ outL,
           u16* __restrict__ outQ, u16* __restrict__ outK, u16* __restrict__ outV,
           int K, int lda, int ldb, int ldc,
           long aStride, long bStride, long cStride,
           float scale, int mode)
{
    GEMM_CONSTS
    GEMM_PROLOG_ID
    if constexpr (DEC == 1) {
        constexpr int NBY = 512 / BN;
        constexpr int INN = 3 * NBY;
        int inner = id % INN;
        by = inner % NBY;
        bz = inner / NBY;
        bx = id / INN;
    } else {
        bx = id % gx;
        by = (id / gx) % gy;
        bz = id / (gx * gy);
    }
    GEMM_PROLOG_BODY
    constexpr int EPI1 = (1 + ELO) * 128*(BN+12);
    constexpr int EPI2 = BN * 136;
    constexpr int EPIM = (EPI1 > EPI2) ? EPI1 : EPI2;
    constexpr int LDSN = (3*BUFSZ > EPIM) ? 3*BUFSZ : EPIM;
    __shared__ u16 lds[LDSN];
    auto stage = [&](int buf, int k0) {
        #pragma unroll
        for (int i = 0; i < CPW; ++i)
            __builtin_amdgcn_global_load_lds(
                (const __attribute__((address_space(1))) unsigned int*)(csrc[i] + k0),
                (__attribute__((address_space(3))) unsigned int*)(&lds[buf * BUFSZ + cdst[i]]),
                16, 0, 0);
    };
    const int nt = K >> 5;
    stage(0, 0);
    stage(1, 32);
    for (int t = 0; t < nt; ++t) {
        if (t + 1 < nt) waitv<CPW>();
        else            waitv<0>();
        __builtin_amdgcn_s_barrier();
        __builtin_amdgcn_sched_barrier(0);
        if (t + 2 < nt) stage((t + 2) % 3, (t + 2) << 5);
        GEMM_COMPUTE((t % 3) * BUFSZ)
    }
    int emode = mode; const float* ebias = bias; u16* eoutH = outH; u16* eoutL = outL;
    if (mode == 3) {   // fused QKV: bz selects weight slice & destination
        emode = (bz == 2) ? 2 : 1;
        ebias = bias + bz * 512;
        eoutH = (bz == 0) ? outQ : (bz == 1) ? outK : outV;
        eoutL = nullptr;
    }
    GEMM_EPILOG_STAGED
}

// ---- 256x256 tile, 16-wave (4x4), 1024 threads, BK=64, swizzled (scores) ----
__global__ __launch_bounds__(1024, 4)
void gemm256w(const u16* __restrict__ A, const u16* __restrict__ B,
              u16* __restrict__ outH,
              int K, int lda, int ldb, int ldc,
              long aStride, long bStride, long cStride, float scale)
{
    __shared__ u16 lds[2 * 32768];          // 128 KB; epilogue reuses [128][264]
    const int tid  = threadIdx.x;
    const int lane = tid & 63;
    const int wave = tid >> 6;              // 0..15
    const int wr = wave >> 2, wc = wave & 3;

    // XCD-aware swizzle (grid %8==0)
    const int gx = gridDim.x, gy = gridDim.y;
    int nwg = gx * gy * gridDim.z;
    int wg  = blockIdx.x + gx * (blockIdx.y + gy * blockIdx.z);
    int id  = (wg & 7) * (nwg >> 3) + (wg >> 3);
    const int bx = id % gx;
    const int by = (id / gx) % gy;
    const int bz = id / (gx * gy);

    const long aBase = (long)bz * aStride + (long)(bx * 256) * lda;
    const long bBase = (long)bz * bStride + (long)(by * 256) * ldb;

    const int sw     = wave & 7;
    const bool isB   = wave >= 8;
    const int srow   = lane >> 3;                       // 0..7
    const int schunk = (lane & 7) ^ (srow & 7);         // inverse-swizzled src chunk
    const u16* src_[4];
    unsigned  dst_[4];
    #pragma unroll
    for (int i = 0; i < 4; ++i) {
        int rb = sw * 8 + i * 64;
        src_[i] = (isB ? B + bBase : A + aBase)
                + (long)(rb + srow) * (isB ? ldb : lda) + schunk * 8;
        dst_[i] = (isB ? 16384 : 0) + rb * 64;
    }
    auto stage = [&](int buf, int k0) {
        #pragma unroll
        for (int i = 0; i < 4; ++i)
            __builtin_amdgcn_global_load_lds(
                (const __attribute__((address_space(1))) unsigned int*)(src_[i] + k0),
                (__attribute__((address_space(3))) unsigned int*)(&lds[buf * 32768 + dst_[i]]),
                16, 0, 0);
    };

    f32x4 acc[4][4] = {};
    const int frow = lane & 15;
    const int kq   = lane >> 4;
    const int fswz = frow & 7;

    const int nt = K >> 6;                  // BK=64
    stage(0, 0);
    stage(1, 64);
    for (int t = 0; t < nt; ++t) {
        if (t + 1 < nt) waitv<4>(); else waitv<0>();
        __builtin_amdgcn_s_barrier();
        __builtin_amdgcn_sched_barrier(0);
        const int bb = (t & 1) * 32768;
        #pragma unroll
        for (int kh = 0; kh < 2; ++kh) {
            const int ch = ((kh << 2) + kq) ^ fswz;
            bf16x8 aH[4], bH[4];
            #pragma unroll
            for (int m = 0; m < 4; ++m) {
                int rA = wr*64 + m*16 + frow;
                aH[m] = *(const bf16x8*)&lds[bb + rA*64 + ch*8];
            }
            #pragma unroll
            for (int n = 0; n < 4; ++n) {
                int rB = wc*64 + n*16 + frow;
                bH[n] = *(const bf16x8*)&lds[bb + 16384 + rB*64 + ch*8];
            }
            #pragma unroll
            for (int m = 0; m < 4; ++m)
                #pragma unroll
                for (int n = 0; n < 4; ++n)
                    acc[m][n] = __builtin_amdgcn_mfma_f32_16x16x32_bf16(aH[m], bH[n], acc[m][n], 0, 0, 0);
        }
        __builtin_amdgcn_s_barrier();
        __builtin_amdgcn_sched_barrier(0);
        if (t + 2 < nt) stage(t & 1, (t + 2) << 6);
    }

    const int rr = (lane >> 4) * 4;
    #pragma unroll
    for (int h = 0; h < 2; ++h) {
        __syncthreads();
        if ((wr >> 1) == h) {
            #pragma unroll
            for (int n = 0; n < 4; ++n) {
                int c = wc*64 + n*16 + frow;
                #pragma unroll
                for (int m = 0; m < 4; ++m)
                    #pragma unroll
                    for (int j = 0; j < 4; ++j)
                        lds[((wr & 1)*64 + m*16 + rr + j)*264 + c] = f2bf(acc[m][n][j] * scale);
            }
        }
        __syncthreads();
        for (int idx = tid; idx < 128*32; idx += 1024) {
            int row = idx >> 5, c8 = (idx & 31) * 8;
            *(bf16x8*)&outH[(long)bz*cStride + (long)(bx*256 + h*128 + row)*ldc + by*256 + c8] =
                *(bf16x8*)&lds[row*264 + c8];
        }
    }
}

// ---------------- row softmax over 2048, in-place, bf16 ----------------
__global__ __launch_bounds__(256)
void softmax_kernel(u16* __restrict__ sh)
{
    const long base = (long)blockIdx.x * 2048;
    const int tid = threadIdx.x;
    const int lane = tid & 63, wave = tid >> 6;
    u16* hp = sh + base + tid * 8;
    bf16x8 hv = *(const bf16x8*)hp;
    float s[8];
    #pragma unroll
    for (int j = 0; j < 8; ++j) s[j] = bf2f((u16)hv[j]);

    float mx = s[0];
    #pragma unroll
    for (int j = 1; j < 8; ++j) mx = fmaxf(mx, s[j]);
    #pragma unroll
    for (int off = 32; off >= 1; off >>= 1) mx = fmaxf(mx, __shfl_xor(mx, off));
    __shared__ float red[8];
    if (lane == 0) red[wave] = mx;
    __syncthreads();
    mx = fmaxf(fmaxf(red[0], red[1]), fmaxf(red[2], red[3]));

    float e[8], sum = 0.f;
    #pragma unroll
    for (int j = 0; j < 8; ++j) { e[j] = __expf(s[j] - mx); sum += e[j]; }
    #pragma unroll
    for (int off = 32; off >= 1; off >>= 1) sum += __shfl_xor(sum, off);
    if (lane == 0) red[4 + wave] = sum;
    __syncthreads();
    sum = red[4] + red[5] + red[6] + red[7];
    float inv = 1.0f / sum;

    bf16x8 ho;
    #pragma unroll
    for (int j = 0; j < 8; ++j) ho[j] = (short)f2bf(e[j] * inv);
    *(bf16x8*)hp = ho;
}

extern "C" void kernel_launch(void* const* d_in, const int* in_sizes, int n_in,
                              void* d_out, int out_size, void* d_ws, size_t ws_size,
                              hipStream_t stream)
{
    const float* x  = (const float*)d_in[0];
    const float* Wq = (const float*)d_in[1];
    const float* bq = (const float*)d_in[2];
    const float* Wk = (const float*)d_in[3];
    const float* bk = (const float*)d_in[4];
    const float* Wv = (const float*)d_in[5];
    const float* bv = (const float*)d_in[6];
    const float* Wo = (const float*)d_in[7];
    const float* bo = (const float*)d_in[8];

    char* p = (char*)d_ws;
    auto alloc = [&](size_t bytes) { char* r = p; p += (bytes + 255) & ~(size_t)255; return r; };

    const size_t XE = (size_t)ROWS * D_MODEL;     // 4,194,304
    const size_t WE = (size_t)D_MODEL * D_MODEL;  // 262,144
    const size_t SE = (size_t)BATCH * SEQ * SEQ;  // 16,777,216

    u16* xh   = (u16*)alloc(XE * 2);
    u16* xl   = (u16*)alloc(XE * 2);      // used only as att-lo (aliased below)
    u16* whh  = (u16*)alloc(3 * WE * 2);  // concat Wq,Wk,Wv (hi only)
    u16* woh  = (u16*)alloc(WE * 2);
    float* bqkv = (float*)alloc(1536 * 4);
    u16* qh   = (u16*)alloc(XE * 2);
    u16* kh   = (u16*)alloc(XE * 2);
    u16* vTh  = (u16*)alloc(XE * 2);
    u16* sh   = (u16*)alloc(SE * 2);
    // att (split) aliases x buffers — x dead after QKV projection
    u16* ath = xh;
    u16* atl = xl;

    // 1. fused prep (1 launch): x -> hi; weights -> hi; bias concat
    prep_kernel<<<5126, 256, 0, stream>>>(x, Wq, Wk, Wv, Wo, bq, bk, bv,
                                          xh, whh, woh, bqkv);

    // 2. fused QKV projection: 1-term, ring-3, BN=128 (NF=4), panel-major,
    //    ELO=0 hi-only epilogue (r24-measured ~20 us, VGPR 88)
    gemm3<4,1,1,1,0><<<dim3(768, 1, 1), 256, 0, stream>>>(xh, nullptr, whh, nullptr, bqkv,
        nullptr, nullptr, nullptr, qh, kh, vTh,
        512, 512, 512, 512, 0, (long)WE, 0, 1.0f, 3);

    // 3. scores = q@k^T * 1/sqrt(512): 256^2, 16 waves, swizzled, counted
    gemm256w<<<dim3(8, 8, 4), 1024, 0, stream>>>(qh, kh, sh,
        512, 512, 512, 2048,
        (long)SEQ * 512, (long)SEQ * 512, (long)SEQ * SEQ,
        0.044194173824159216f);

    // 4. softmax rows (bf16 in/out)
    softmax_kernel<<<ROWS, 256, 0, stream>>>(sh);

    // 5. att = p @ v: 1-term, ring-3, NF=2 grid (16,8,4) = 512 blocks,
    //    ELO=1 hi+lo double-buffer epilogue (r21/r23-measured 42 us)
    gemm3<2,1,1,0,1><<<dim3(16, 8, 4), 256, 0, stream>>>(sh, nullptr, vTh, nullptr, nullptr,
        nullptr, ath, atl, nullptr, nullptr, nullptr,
        2048, 2048, 2048, 512,
        (long)SEQ * SEQ, (long)512 * SEQ, (long)SEQ * 512,
        1.0f, 1);

    // 6. out = att @ Wo^T + bo: 2-term (att_hi + att_lo) * Wo_hi, fp32 out
    gemm2<2,2,1><<<dim3(64, 8, 1), 256, 0, stream>>>(ath, atl, woh, nullptr, bo,
        (float*)d_out, nullptr, nullptr, 512, 512, 512, 512,
        0, 0, 0, 1.0f, 0);
}

// Round 28
// 126.258 us; speedup vs baseline: 1.0552x; 1.0029x over previous
//
#include <hip/hip_runtime.h>
#include <hip/hip_bf16.h>

#define D_MODEL 512
#define BATCH 4
#define SEQ 2048
#define ROWS (BATCH*SEQ)   // 8192

typedef unsigned short u16;
typedef short bf16x8 __attribute__((ext_vector_type(8)));
typedef float f32x4 __attribute__((ext_vector_type(4)));

__device__ __forceinline__ float bf2f(u16 u) {
    union { unsigned int i; float f; } v;
    v.i = ((unsigned int)u) << 16;
    return v.f;
}
__device__ __forceinline__ u16 f2bf(float f) {
    union { float f; unsigned int i; } v;
    v.f = f;
    unsigned int x = v.i;
    unsigned int r = (x >> 16) & 1u;
    x += 0x7fffu + r;           // round-to-nearest-even
    return (u16)(x >> 16);
}

template<int N> __device__ __forceinline__ void waitv() {
    static_assert(N==0 || N==1 || N==3 || N==4 || N==5 || N==8, "unsupported vmcnt");
    if constexpr (N == 0) asm volatile("s_waitcnt vmcnt(0)" ::: "memory");
    if constexpr (N == 1) asm volatile("s_waitcnt vmcnt(1)" ::: "memory");
    if constexpr (N == 3) asm volatile("s_waitcnt vmcnt(3)" ::: "memory");
    if constexpr (N == 4) asm volatile("s_waitcnt vmcnt(4)" ::: "memory");
    if constexpr (N == 5) asm volatile("s_waitcnt vmcnt(5)" ::: "memory");
    if constexpr (N == 8) asm volatile("s_waitcnt vmcnt(8)" ::: "memory");
}

// ---------------- fused prep: x -> hi only; weights hi-only; bias concat ----
__global__ __launch_bounds__(256)
void prep_kernel(const float* __restrict__ x,
                 const float* __restrict__ Wq, const float* __restrict__ Wk,
                 const float* __restrict__ Wv, const float* __restrict__ Wo,
                 const float* __restrict__ bq, const float* __restrict__ bk,
                 const float* __restrict__ bv,
                 u16* __restrict__ xh,
                 u16* __restrict__ whh, u16* __restrict__ woh,
                 float* __restrict__ bqkv)
{
    const int blk = blockIdx.x;
    const int tid = threadIdx.x;
    const int WE = 262144;
    if (blk >= 5120) {
        int i = (blk - 5120) * 256 + tid;
        if (i < 1536)
            bqkv[i] = (i < 512) ? bq[i] : (i < 1024) ? bk[i - 512] : bv[i - 1024];
        return;
    }
    const float* src; u16 *dh; int i;
    if (blk < 4096) {
        src = x; dh = xh;
        i = (blk * 256 + tid) * 4;
    } else {
        int w = (blk - 4096) >> 8;
        src = (w == 0) ? Wq : (w == 1) ? Wk : (w == 2) ? Wv : Wo;
        dh  = (w < 3) ? whh + w * WE : woh;
        i = (((blk - 4096) & 255) * 256 + tid) * 4;
    }
    float4 v = *(const float4*)(src + i);
    u16 hh[4] = { f2bf(v.x), f2bf(v.y), f2bf(v.z), f2bf(v.w) };
    *(ushort4*)(dh + i) = make_ushort4(hh[0], hh[1], hh[2], hh[3]);
}

// ======== shared GEMM pieces ========
#define GEMM_PROLOG_ID                                                         \
    const int tid  = threadIdx.x;                                              \
    const int lane = tid & 63;                                                 \
    const int wave = tid >> 6;                                                 \
    const int wr = wave >> 1, wc = wave & 1;                                   \
    const int gx = gridDim.x, gy = gridDim.y;                                  \
    int nwg = gx * gy * gridDim.z;                                             \
    int wg  = blockIdx.x + gx * (blockIdx.y + gy * blockIdx.z);                \
    int id  = (wg & 7) * (nwg >> 3) + (wg >> 3);                               \
    int bx, by, bz;

#define GEMM_PROLOG_BODY                                                       \
    const long aBase = (long)bz * aStride + (long)(bx * 128) * lda;            \
    const long bBase = (long)bz * bStride + (long)(by * BN) * ldb;             \
    const u16* csrc[CPW];                                                      \
    unsigned cdst[CPW];                                                        \
    _Pragma("unroll")                                                          \
    for (int i = 0; i < CPW; ++i) {                                            \
        int c = wave + i * 4;                                                  \
        const u16* sb; int ld, lofs, row;                                      \
        if (c < AT * ACH) {                                                    \
            int t = c >> 3;                                                    \
            row = (c & 7) * 16;                                                \
            sb = (t == 0 ? Ah : Al) + aBase;                                   \
            ld = lda; lofs = t * TILE_A;                                       \
        } else {                                                               \
            int cb = c - AT * ACH;                                             \
            int t = cb / BCH;                                                  \
            row = (cb % BCH) * 16;                                             \
            sb = (t == 0 ? Bh : Bl) + bBase;                                   \
            ld = ldb; lofs = AT * TILE_A + t * TILE_B;                         \
        }                                                                      \
        csrc[i] = sb + (long)(row + (lane >> 2)) * ld + (lane & 3) * 8;        \
        cdst[i] = lofs + row * 32;                                             \
    }                                                                          \
    f32x4 acc[4][NF] = {};                                                     \
    const int frow = lane & 15;                                                \
    const int kofs = (lane >> 4) * 8;

#define GEMM_CONSTS                                                            \
    constexpr int BN     = 32 * NF;                                            \
    constexpr int TILE_A = 128 * 32;                                           \
    constexpr int TILE_B = BN * 32;                                            \
    constexpr int ACH    = 8;                                                  \
    constexpr int BCH    = BN / 16;                                            \
    constexpr int NCH    = AT*ACH + BT*BCH;                                    \
    constexpr int CPW    = NCH / 4;                                            \
    constexpr int BUFSZ  = AT*TILE_A + BT*TILE_B;

#define GEMM_COMPUTE(bb_)                                                      \
    {                                                                          \
        const int bb = (bb_);                                                  \
        bf16x8 aH[4], aL[4], bH[NF], bL[NF];                                   \
        _Pragma("unroll")                                                      \
        for (int m = 0; m < 4; ++m) {                                          \
            int rA = wr*64 + m*16 + frow;                                      \
            aH[m] = *(const bf16x8*)&lds[bb + rA*32 + kofs];                   \
            if constexpr (AT == 2)                                             \
                aL[m] = *(const bf16x8*)&lds[bb + TILE_A + rA*32 + kofs];      \
        }                                                                      \
        _Pragma("unroll")                                                      \
        for (int n = 0; n < NF; ++n) {                                         \
            int rB = wc*(NF*16) + n*16 + frow;                                 \
            bH[n] = *(const bf16x8*)&lds[bb + AT*TILE_A + rB*32 + kofs];       \
            if constexpr (BT == 2)                                             \
                bL[n] = *(const bf16x8*)&lds[bb + AT*TILE_A + TILE_B + rB*32 + kofs]; \
        }                                                                      \
        _Pragma("unroll")                                                      \
        for (int m = 0; m < 4; ++m)                                            \
            _Pragma("unroll")                                                  \
            for (int n = 0; n < NF; ++n) {                                     \
                acc[m][n] = __builtin_amdgcn_mfma_f32_16x16x32_bf16(aH[m], bH[n], acc[m][n], 0, 0, 0); \
                if constexpr (BT == 2)                                         \
                    acc[m][n] = __builtin_amdgcn_mfma_f32_16x16x32_bf16(aH[m], bL[n], acc[m][n], 0, 0, 0); \
                if constexpr (AT == 2)                                         \
                    acc[m][n] = __builtin_amdgcn_mfma_f32_16x16x32_bf16(aL[m], bH[n], acc[m][n], 0, 0, 0); \
            }                                                                  \
    }

// Staged epilogue (uses emode/ebias/eoutH/eoutL, set per-kernel before use).
#define GEMM_EPILOG_STAGED                                                     \
    {                                                                          \
    const int rr = (lane >> 4) * 4;                                            \
    __syncthreads();                                                           \
    if (emode == 0) {                                                          \
        float* ldsF = (float*)lds;                                             \
        _Pragma("unroll")                                                      \
        for (int n = 0; n < NF; ++n) {                                         \
            int c = wc*(NF*16) + n*16 + frow;                                  \
            float bv_ = ebias ? ebias[by*BN + c] : 0.0f;                       \
            _Pragma("unroll")                                                  \
            for (int m = 0; m < 4; ++m)                                        \
                _Pragma("unroll")                                              \
                for (int j = 0; j < 4; ++j)                                    \
                    ldsF[(wr*64 + m*16 + rr + j)*(BN+4) + c] = acc[m][n][j]*scale + bv_; \
        }                                                                      \
        __syncthreads();                                                       \
        for (int idx = tid; idx < 128*(BN/4); idx += 256) {                    \
            int row = idx / (BN/4), c4 = (idx % (BN/4)) * 4;                   \
            *(float4*)&outF[(long)bz*cStride + (long)(bx*128+row)*ldc + by*BN + c4] = \
                *(float4*)&ldsF[row*(BN+4) + c4];                              \
        }                                                                      \
    } else if (emode == 1) {                                                   \
        u16* ldsH = (u16*)lds;                                                 \
        u16* ldsL = (u16*)lds + 128*(BN+12);                                   \
        _Pragma("unroll")                                                      \
        for (int n = 0; n < NF; ++n) {                                         \
            int c = wc*(NF*16) + n*16 + frow;                                  \
            float bv_ = ebias ? ebias[by*BN + c] : 0.0f;                       \
            _Pragma("unroll")                                                  \
            for (int m = 0; m < 4; ++m)                                        \
                _Pragma("unroll")                                              \
                for (int j = 0; j < 4; ++j) {                                  \
                    int r = wr*64 + m*16 + rr + j;                             \
                    float val = acc[m][n][j]*scale + bv_;                      \
                    u16 h = f2bf(val);                                         \
                    ldsH[r*(BN+12) + c] = h;                                   \
                    if (eoutL) ldsL[r*(BN+12) + c] = f2bf(val - bf2f(h));      \
                }                                                              \
        }                                                                      \
        __syncthreads();                                                       \
        for (int idx = tid; idx < 128*(BN/8); idx += 256) {                    \
            int row = idx / (BN/8), c8 = (idx % (BN/8)) * 8;                   \
            long o = (long)bz*cStride + (long)(bx*128+row)*ldc + by*BN + c8;   \
            *(bf16x8*)&eoutH[o] = *(bf16x8*)&ldsH[row*(BN+12) + c8];           \
            if (eoutL) *(bf16x8*)&eoutL[o] = *(bf16x8*)&ldsL[row*(BN+12) + c8]; \
        }                                                                      \
    } else {                                                                   \
        u16* ldsT = (u16*)lds;   /* [BN][136]: transposed tile */              \
        _Pragma("unroll")                                                      \
        for (int n = 0; n < NF; ++n) {                                         \
            int c = wc*(NF*16) + n*16 + frow;                                  \
            float bv_ = ebias ? ebias[by*BN + c] : 0.0f;                       \
            _Pragma("unroll")                                                  \
            for (int m = 0; m < 4; ++m)                                        \
                _Pragma("unroll")                                              \
                for (int j = 0; j < 4; ++j)                                    \
                    ldsT[c*136 + (wr*64 + m*16 + rr + j)] = f2bf(acc[m][n][j]*scale + bv_); \
        }                                                                      \
        __syncthreads();                                                       \
        int b = bx >> 4, mrowBase = (bx & 15) * 128;                           \
        for (int idx = tid; idx < BN*16; idx += 256) {                         \
            int crow = idx >> 4, r8 = (idx & 15) * 8;                          \
            *(bf16x8*)&eoutH[(long)b*1048576 + (long)(by*BN + crow)*2048 + mrowBase + r8] = \
                *(bf16x8*)&ldsT[crow*136 + r8];                                \
        }                                                                      \
    }                                                                          \
    }

// ---- 2-buffer variant (final projection) ----
template<int NF, int AT, int BT>
__global__ __launch_bounds__(256)
void gemm2(const u16* __restrict__ Ah, const u16* __restrict__ Al,
           const u16* __restrict__ Bh, const u16* __restrict__ Bl,
           const float* __restrict__ bias,
           float* __restrict__ outF, u16* __restrict__ outH, u16* __restrict__ outL,
           int K, int lda, int ldb, int ldc,
           long aStride, long bStride, long cStride,
           float scale, int mode)
{
    GEMM_CONSTS
    GEMM_PROLOG_ID
    bx = id % gx;
    by = (id / gx) % gy;
    bz = id / (gx * gy);
    GEMM_PROLOG_BODY
    constexpr int EPI1 = 2 * 128*(BN+12);
    constexpr int EPI0 = 256*(BN+4);
    constexpr int L1   = (2*BUFSZ > EPI1) ? 2*BUFSZ : EPI1;
    constexpr int LDSN = (L1 > EPI0) ? L1 : EPI0;
    __shared__ u16 lds[LDSN];
    auto stage = [&](int buf, int k0) {
        #pragma unroll
        for (int i = 0; i < CPW; ++i)
            __builtin_amdgcn_global_load_lds(
                (const __attribute__((address_space(1))) unsigned int*)(csrc[i] + k0),
                (__attribute__((address_space(3))) unsigned int*)(&lds[buf * BUFSZ + cdst[i]]),
                16, 0, 0);
    };
    const int nt = K >> 5;
    stage(0, 0);
    __syncthreads();
    int cur = 0;
    for (int t = 0; t < nt; ++t) {
        if (t + 1 < nt) stage(cur ^ 1, (t + 1) << 5);
        GEMM_COMPUTE(cur * BUFSZ)
        __syncthreads();
        cur ^= 1;
    }
    int emode = mode; const float* ebias = bias; u16* eoutH = outH; u16* eoutL = outL;
    GEMM_EPILOG_STAGED
}

// ---- ring-3 counted-vmcnt variant ----
// DEC=1 (QKV fused): inner=id%(3*(512/BN)) -> (by, bz weight-slice), bx outer.
// ELO: epilogue LDS sized for hi+lo (1) or hi-only (0).
template<int NF, int AT, int BT, int DEC = 0, int ELO = 1>
__global__ __launch_bounds__(256)
void gemm3(const u16* __restrict__ Ah, const u16* __restrict__ Al,
           const u16* __restrict__ Bh, const u16* __restrict__ Bl,
           const float* __restrict__ bias,
           float* __restrict__ outF, u16* __restrict__ outH, u16* __restrict__ outL,
           u16* __restrict__ outQ, u16* __restrict__ outK, u16* __restrict__ outV,
           int K, int lda, int ldb, int ldc,
           long aStride, long bStride, long cStride,
           float scale, int mode)
{
    GEMM_CONSTS
    GEMM_PROLOG_ID
    if constexpr (DEC == 1) {
        constexpr int NBY = 512 / BN;
        constexpr int INN = 3 * NBY;
        int inner = id % INN;
        by = inner % NBY;
        bz = inner / NBY;
        bx = id / INN;
    } else {
        bx = id % gx;
        by = (id / gx) % gy;
        bz = id / (gx * gy);
    }
    GEMM_PROLOG_BODY
    constexpr int EPI1 = (1 + ELO) * 128*(BN+12);
    constexpr int EPI2 = BN * 136;
    constexpr int EPIM = (EPI1 > EPI2) ? EPI1 : EPI2;
    constexpr int LDSN = (3*BUFSZ > EPIM) ? 3*BUFSZ : EPIM;
    __shared__ u16 lds[LDSN];
    auto stage = [&](int buf, int k0) {
        #pragma unroll
        for (int i = 0; i < CPW; ++i)
            __builtin_amdgcn_global_load_lds(
                (const __attribute__((address_space(1))) unsigned int*)(csrc[i] + k0),
                (__attribute__((address_space(3))) unsigned int*)(&lds[buf * BUFSZ + cdst[i]]),
                16, 0, 0);
    };
    const int nt = K >> 5;
    stage(0, 0);
    stage(1, 32);
    for (int t = 0; t < nt; ++t) {
        if (t + 1 < nt) waitv<CPW>();
        else            waitv<0>();
        __builtin_amdgcn_s_barrier();
        __builtin_amdgcn_sched_barrier(0);
        if (t + 2 < nt) stage((t + 2) % 3, (t + 2) << 5);
        GEMM_COMPUTE((t % 3) * BUFSZ)
    }
    int emode = mode; const float* ebias = bias; u16* eoutH = outH; u16* eoutL = outL;
    if (mode == 3) {   // fused QKV: bz selects weight slice & destination
        emode = (bz == 2) ? 2 : 1;
        ebias = bias + bz * 512;
        eoutH = (bz == 0) ? outQ : (bz == 1) ? outK : outV;
        eoutL = nullptr;
    }
    GEMM_EPILOG_STAGED
}

// ---- PV: 1024-thread, 16-wave (4x4, wave tile 32x32), BM=BN=128, BK=32,
// ring-3 counted vmcnt (CPW=1/thread), sequential hi/lo epilogue.
// Grid 256 = 16 bx * (4 by * 4 bz); 2 blocks/CU = 32 waves/CU.
__global__ __launch_bounds__(1024)
void pv16(const u16* __restrict__ A, const u16* __restrict__ B,
          u16* __restrict__ outH, u16* __restrict__ outL,
          int K, int lda, int ldb, int ldc,
          long aStride, long bStride, long cStride, float scale)
{
    constexpr int BUFSZ = 8192;             // (128x32 A + 128x32 B) u16
    __shared__ u16 lds[3 * BUFSZ];          // 48 KB; epilogue reuses [128][140]
    const int tid  = threadIdx.x;
    const int lane = tid & 63;
    const int wave = tid >> 6;              // 0..15
    const int wr = wave >> 2, wc = wave & 3;

    // XCD swizzle + DEC2 decode (grid 256 %8==0)
    int nwg = gridDim.x;
    int wg  = blockIdx.x;
    int id  = (wg & 7) * (nwg >> 3) + (wg >> 3);
    const int by = id & 3;
    const int bz = (id >> 2) & 3;
    const int bx = id >> 4;

    const long aBase = (long)bz * aStride + (long)(bx * 128) * lda;
    const long bBase = (long)bz * bStride + (long)(by * 128) * ldb;

    // staging: waves 0-7 -> A rows 16w..16w+15; waves 8-15 -> B rows likewise.
    // 1 global_load_lds per thread per K-step (16 KB block staging).
    const bool isB = wave >= 8;
    const int  cw  = wave & 7;
    const u16* csrc = (isB ? B + bBase : A + aBase)
                    + (long)(cw * 16 + (lane >> 2)) * (isB ? ldb : lda)
                    + (lane & 3) * 8;
    const unsigned cdst = (isB ? 4096 : 0) + cw * 512;

    auto stage = [&](int buf, int k0) {
        __builtin_amdgcn_global_load_lds(
            (const __attribute__((address_space(1))) unsigned int*)(csrc + k0),
            (__attribute__((address_space(3))) unsigned int*)(&lds[buf * BUFSZ + cdst]),
            16, 0, 0);
    };

    f32x4 acc[2][2] = {};
    const int frow = lane & 15;
    const int kofs = (lane >> 4) * 8;

    const int nt = K >> 5;                  // 64
    stage(0, 0);
    stage(1, 32);
    for (int t = 0; t < nt; ++t) {
        if (t + 1 < nt) waitv<1>();         // stage(t) done, stage(t+1) in flight
        else            waitv<0>();
        __builtin_amdgcn_s_barrier();
        __builtin_amdgcn_sched_barrier(0);
        if (t + 2 < nt) stage((t + 2) % 3, (t + 2) << 5);
        const int bb = (t % 3) * BUFSZ;
        bf16x8 aH[2], bH[2];
        #pragma unroll
        for (int m = 0; m < 2; ++m) {
            int rA = wr*32 + m*16 + frow;
            aH[m] = *(const bf16x8*)&lds[bb + rA*32 + kofs];
        }
        #pragma unroll
        for (int n = 0; n < 2; ++n) {
            int rB = wc*32 + n*16 + frow;
            bH[n] = *(const bf16x8*)&lds[bb + 4096 + rB*32 + kofs];
        }
        #pragma unroll
        for (int m = 0; m < 2; ++m)
            #pragma unroll
            for (int n = 0; n < 2; ++n)
                acc[m][n] = __builtin_amdgcn_mfma_f32_16x16x32_bf16(aH[m], bH[n], acc[m][n], 0, 0, 0);
    }

    // sequential hi/lo epilogue through [128][140] (35 KB < 48 KB)
    const int rr = (lane >> 4) * 4;
    #pragma unroll
    for (int part = 0; part < 2; ++part) {
        u16* dstG = part ? outL : outH;
        __syncthreads();
        #pragma unroll
        for (int n = 0; n < 2; ++n) {
            int c = wc*32 + n*16 + frow;
            #pragma unroll
            for (int m = 0; m < 2; ++m)
                #pragma unroll
                for (int j = 0; j < 4; ++j) {
                    int r = wr*32 + m*16 + rr + j;
                    float val = acc[m][n][j] * scale;
                    u16 h = f2bf(val);
                    lds[r*140 + c] = part ? f2bf(val - bf2f(h)) : h;
                }
        }
        __syncthreads();
        for (int idx = tid; idx < 128*16; idx += 1024) {
            int row = idx >> 4, c8 = (idx & 15) * 8;
            *(bf16x8*)&dstG[(long)bz*cStride + (long)(bx*128+row)*ldc + by*128 + c8] =
                *(bf16x8*)&lds[row*140 + c8];
        }
    }
}

// ---- 256x256 tile, 16-wave (4x4), 1024 threads, BK=64, swizzled (scores) ----
__global__ __launch_bounds__(1024, 4)
void gemm256w(const u16* __restrict__ A, const u16* __restrict__ B,
              u16* __restrict__ outH,
              int K, int lda, int ldb, int ldc,
              long aStride, long bStride, long cStride, float scale)
{
    __shared__ u16 lds[2 * 32768];          // 128 KB; epilogue reuses [128][264]
    const int tid  = threadIdx.x;
    const int lane = tid & 63;
    const int wave = tid >> 6;              // 0..15
    const int wr = wave >> 2, wc = wave & 3;

    // XCD-aware swizzle (grid %8==0)
    const int gx = gridDim.x, gy = gridDim.y;
    int nwg = gx * gy * gridDim.z;
    int wg  = blockIdx.x + gx * (blockIdx.y + gy * blockIdx.z);
    int id  = (wg & 7) * (nwg >> 3) + (wg >> 3);
    const int bx = id % gx;
    const int by = (id / gx) % gy;
    const int bz = id / (gx * gy);

    const long aBase = (long)bz * aStride + (long)(bx * 256) * lda;
    const long bBase = (long)bz * bStride + (long)(by * 256) * ldb;

    const int sw     = wave & 7;
    const bool isB   = wave >= 8;
    const int srow   = lane >> 3;                       // 0..7
    const int schunk = (lane & 7) ^ (srow & 7);         // inverse-swizzled src chunk
    const u16* src_[4];
    unsigned  dst_[4];
    #pragma unroll
    for (int i = 0; i < 4; ++i) {
        int rb = sw * 8 + i * 64;
        src_[i] = (isB ? B + bBase : A + aBase)
                + (long)(rb + srow) * (isB ? ldb : lda) + schunk * 8;
        dst_[i] = (isB ? 16384 : 0) + rb * 64;
    }
    auto stage = [&](int buf, int k0) {
        #pragma unroll
        for (int i = 0; i < 4; ++i)
            __builtin_amdgcn_global_load_lds(
                (const __attribute__((address_space(1))) unsigned int*)(src_[i] + k0),
                (__attribute__((address_space(3))) unsigned int*)(&lds[buf * 32768 + dst_[i]]),
                16, 0, 0);
    };

    f32x4 acc[4][4] = {};
    const int frow = lane & 15;
    const int kq   = lane >> 4;
    const int fswz = frow & 7;

    const int nt = K >> 6;                  // BK=64
    stage(0, 0);
    stage(1, 64);
    for (int t = 0; t < nt; ++t) {
        if (t + 1 < nt) waitv<4>(); else waitv<0>();
        __builtin_amdgcn_s_barrier();
        __builtin_amdgcn_sched_barrier(0);
        const int bb = (t & 1) * 32768;
        #pragma unroll
        for (int kh = 0; kh < 2; ++kh) {
            const int ch = ((kh << 2) + kq) ^ fswz;
            bf16x8 aH[4], bH[4];
            #pragma unroll
            for (int m = 0; m < 4; ++m) {
                int rA = wr*64 + m*16 + frow;
                aH[m] = *(const bf16x8*)&lds[bb + rA*64 + ch*8];
            }
            #pragma unroll
            for (int n = 0; n < 4; ++n) {
                int rB = wc*64 + n*16 + frow;
                bH[n] = *(const bf16x8*)&lds[bb + 16384 + rB*64 + ch*8];
            }
            #pragma unroll
            for (int m = 0; m < 4; ++m)
                #pragma unroll
                for (int n = 0; n < 4; ++n)
                    acc[m][n] = __builtin_amdgcn_mfma_f32_16x16x32_bf16(aH[m], bH[n], acc[m][n], 0, 0, 0);
        }
        __builtin_amdgcn_s_barrier();
        __builtin_amdgcn_sched_barrier(0);
        if (t + 2 < nt) stage(t & 1, (t + 2) << 6);
    }

    const int rr = (lane >> 4) * 4;
    #pragma unroll
    for (int h = 0; h < 2; ++h) {
        __syncthreads();
        if ((wr >> 1) == h) {
            #pragma unroll
            for (int n = 0; n < 4; ++n) {
                int c = wc*64 + n*16 + frow;
                #pragma unroll
                for (int m = 0; m < 4; ++m)
                    #pragma unroll
                    for (int j = 0; j < 4; ++j)
                        lds[((wr & 1)*64 + m*16 + rr + j)*264 + c] = f2bf(acc[m][n][j] * scale);
            }
        }
        __syncthreads();
        for (int idx = tid; idx < 128*32; idx += 1024) {
            int row = idx >> 5, c8 = (idx & 31) * 8;
            *(bf16x8*)&outH[(long)bz*cStride + (long)(bx*256 + h*128 + row)*ldc + by*256 + c8] =
                *(bf16x8*)&lds[row*264 + c8];
        }
    }
}

// ---------------- row softmax over 2048, in-place, bf16 ----------------
__global__ __launch_bounds__(256)
void softmax_kernel(u16* __restrict__ sh)
{
    const long base = (long)blockIdx.x * 2048;
    const int tid = threadIdx.x;
    const int lane = tid & 63, wave = tid >> 6;
    u16* hp = sh + base + tid * 8;
    bf16x8 hv = *(const bf16x8*)hp;
    float s[8];
    #pragma unroll
    for (int j = 0; j < 8; ++j) s[j] = bf2f((u16)hv[j]);

    float mx = s[0];
    #pragma unroll
    for (int j = 1; j < 8; ++j) mx = fmaxf(mx, s[j]);
    #pragma unroll
    for (int off = 32; off >= 1; off >>= 1) mx = fmaxf(mx, __shfl_xor(mx, off));
    __shared__ float red[8];
    if (lane == 0) red[wave] = mx;
    __syncthreads();
    mx = fmaxf(fmaxf(red[0], red[1]), fmaxf(red[2], red[3]));

    float e[8], sum = 0.f;
    #pragma unroll
    for (int j = 0; j < 8; ++j) { e[j] = __expf(s[j] - mx); sum += e[j]; }
    #pragma unroll
    for (int off = 32; off >= 1; off >>= 1) sum += __shfl_xor(sum, off);
    if (lane == 0) red[4 + wave] = sum;
    __syncthreads();
    sum = red[4] + red[5] + red[6] + red[7];
    float inv = 1.0f / sum;

    bf16x8 ho;
    #pragma unroll
    for (int j = 0; j < 8; ++j) ho[j] = (short)f2bf(e[j] * inv);
    *(bf16x8*)hp = ho;
}

extern "C" void kernel_launch(void* const* d_in, const int* in_sizes, int n_in,
                              void* d_out, int out_size, void* d_ws, size_t ws_size,
                              hipStream_t stream)
{
    const float* x  = (const float*)d_in[0];
    const float* Wq = (const float*)d_in[1];
    const float* bq = (const float*)d_in[2];
    const float* Wk = (const float*)d_in[3];
    const float* bk = (const float*)d_in[4];
    const float* Wv = (const float*)d_in[5];
    const float* bv = (const float*)d_in[6];
    const float* Wo = (const float*)d_in[7];
    const float* bo = (const float*)d_in[8];

    char* p = (char*)d_ws;
    auto alloc = [&](size_t bytes) { char* r = p; p += (bytes + 255) & ~(size_t)255; return r; };

    const size_t XE = (size_t)ROWS * D_MODEL;     // 4,194,304
    const size_t WE = (size_t)D_MODEL * D_MODEL;  // 262,144
    const size_t SE = (size_t)BATCH * SEQ * SEQ;  // 16,777,216

    u16* xh   = (u16*)alloc(XE * 2);
    u16* xl   = (u16*)alloc(XE * 2);      // used only as att-lo (aliased below)
    u16* whh  = (u16*)alloc(3 * WE * 2);  // concat Wq,Wk,Wv (hi only)
    u16* woh  = (u16*)alloc(WE * 2);
    float* bqkv = (float*)alloc(1536 * 4);
    u16* qh   = (u16*)alloc(XE * 2);
    u16* kh   = (u16*)alloc(XE * 2);
    u16* vTh  = (u16*)alloc(XE * 2);
    u16* sh   = (u16*)alloc(SE * 2);
    // att (split) aliases x buffers — x dead after QKV projection
    u16* ath = xh;
    u16* atl = xl;

    // 1. fused prep (1 launch): x -> hi; weights -> hi; bias concat
    prep_kernel<<<5126, 256, 0, stream>>>(x, Wq, Wk, Wv, Wo, bq, bk, bv,
                                          xh, whh, woh, bqkv);

    // 2. fused QKV projection: 1-term, ring-3, BN=128 (NF=4), panel-major,
    //    ELO=0 hi-only epilogue (r24-measured ~20 us)
    gemm3<4,1,1,1,0><<<dim3(768, 1, 1), 256, 0, stream>>>(xh, nullptr, whh, nullptr, bqkv,
        nullptr, nullptr, nullptr, qh, kh, vTh,
        512, 512, 512, 512, 0, (long)WE, 0, 1.0f, 3);

    // 3. scores = q@k^T * 1/sqrt(512): 256^2, 16 waves, swizzled, counted
    gemm256w<<<dim3(8, 8, 4), 1024, 0, stream>>>(qh, kh, sh,
        512, 512, 512, 2048,
        (long)SEQ * 512, (long)SEQ * 512, (long)SEQ * SEQ,
        0.044194173824159216f);

    // 4. softmax rows (bf16 in/out)
    softmax_kernel<<<ROWS, 256, 0, stream>>>(sh);

    // 5. att = p @ v: pv16 — 1024 threads, 16 waves, BK=32, 1 gload/thread/step
    pv16<<<dim3(256, 1, 1), 1024, 0, stream>>>(sh, vTh, ath, atl,
        2048, 2048, 2048, 512,
        (long)SEQ * SEQ, (long)512 * SEQ, (long)SEQ * 512, 1.0f);

    // 6. out = att @ Wo^T + bo: 2-term (att_hi + att_lo) * Wo_hi, fp32 out
    gemm2<2,2,1><<<dim3(64, 8, 1), 256, 0, stream>>>(ath, atl, woh, nullptr, bo,
        (float*)d_out, nullptr, nullptr, 512, 512, 512, 512,
        0, 0, 0, 1.0f, 0);
}